// Round 12
// baseline (404.960 us; speedup 1.0000x reference)
//
#include <hip/hip_runtime.h>
#include <hip/hip_bf16.h>

namespace {
constexpr int kB  = 16;
constexpr int kN  = 3136;
constexpr int kC  = 256;
constexpr int kH  = 8;     // heads
constexpr int kD  = 32;    // head dim
constexpr int kAG = 49;    // agents
constexpr int kHW = 56;
constexpr int kKV = 512;   // kv row stride (k cols 0..255, v cols 256..511)
constexpr int kT   = 112;  // flash tile (2 image rows)
constexpr int kSEG = 7;    // n-segments per (b,h)  (896 blocks -> better occupancy)
constexpr int kTPS = kN / (kT * kSEG);  // 4 tiles per segment
constexpr int kPART = 33;  // per (b,h,seg,a): l, acc[32]

constexpr int BM = 128, BN = 128, BK = 64;
constexpr int LDK = BK + 8;   // bf16 row stride 72 (144 B)

constexpr int kVROWS = 372;   // 256 + 2*58 halo rows for dwc staging
constexpr int kVSTR  = 40;    // ushorts per staged row (80 B, 16B-aligned)
}

typedef __attribute__((ext_vector_type(8))) short short8;
typedef __attribute__((ext_vector_type(8))) unsigned short ushort8;
typedef __attribute__((ext_vector_type(4))) float f32x4;

__device__ __forceinline__ unsigned short f2bf(float f) {
  union { float f; unsigned u; } v; v.f = f;
  unsigned r = (v.u + 0x7FFF + ((v.u >> 16) & 1)) >> 16;  // RNE
  return (unsigned short)r;
}
__device__ __forceinline__ float bf2f(unsigned short u) {
  union { unsigned u; float f; } v; v.u = ((unsigned)u) << 16;
  return v.f;
}

__device__ __forceinline__ float bilin7(const float* __restrict__ tab, int y, int x) {
  // jax.image.resize (7,7)->(56,56) bilinear, half-pixel centers, edge clamp.
  float fy = (y + 0.5f) * 0.125f - 0.5f;
  float fx = (x + 0.5f) * 0.125f - 0.5f;
  float fy0 = floorf(fy), fx0 = floorf(fx);
  float wy = fy - fy0, wx = fx - fx0;
  int y0 = (int)fy0, x0 = (int)fx0;
  int y0c = min(6, max(0, y0)),     x0c = min(6, max(0, x0));
  int y1c = min(6, max(0, y0 + 1)), x1c = min(6, max(0, x0 + 1));
  float v00 = tab[y0c * 7 + x0c], v01 = tab[y0c * 7 + x1c];
  float v10 = tab[y1c * 7 + x0c], v11 = tab[y1c * 7 + x1c];
  float top = v00 + wx * (v01 - v00);
  float bot = v10 + wx * (v11 - v10);
  return top + wy * (bot - top);
}

// ---- bf16-MFMA GEMM: C = A @ B (+bias). A f32 or bf16; C f32 or bf16. ----
template <bool ABF16, bool OUTBF16>
__global__ __launch_bounds__(256) void gemm_mixed_kernel(
    const void* __restrict__ Ap, const float* __restrict__ Bm,
    const float* __restrict__ bias, void* __restrict__ Cp,
    int M, int Nn, int K) {
  __shared__ unsigned short As[BM * LDK];
  __shared__ unsigned short Bs[BN * LDK];
  const int t = threadIdx.x;

  int tx = blockIdx.x, ty = blockIdx.y;
  {
    int nwg = gridDim.x * gridDim.y;
    if ((nwg & 7) == 0) {
      int bid = ty * gridDim.x + tx;
      int per8 = nwg >> 3;
      int lt = (bid & 7) * per8 + (bid >> 3);
      tx = lt % gridDim.x;
      ty = lt / gridDim.x;
    }
  }
  const int row0 = ty * BM;
  const int col0 = tx * BN;
  const int lane = t & 63;
  const int wid  = t >> 6;
  const int wrow = (wid >> 1) * 64;
  const int wcol = (wid & 1) * 64;
  const int lr = lane & 15, lg = lane >> 4;

  f32x4 acc[4][4] = {};

  for (int k0 = 0; k0 < K; k0 += BK) {
    __syncthreads();
    if constexpr (ABF16) {
      const unsigned short* A = (const unsigned short*)Ap;
#pragma unroll
      for (int i = 0; i < 4; ++i) {
        int idx = t + i * 256;
        int r = idx >> 3, k8 = (idx & 7) * 8;
        *(ushort8*)&As[r * LDK + k8] =
            *(const ushort8*)&A[(size_t)(row0 + r) * K + k0 + k8];
      }
    } else {
      const float* A = (const float*)Ap;
#pragma unroll
      for (int i = 0; i < 8; ++i) {
        int idx = t + i * 256;
        int r = idx >> 4, k4 = (idx & 15) * 4;
        float4 f = *(const float4*)&A[(size_t)(row0 + r) * K + k0 + k4];
        unsigned lo = (unsigned)f2bf(f.x) | ((unsigned)f2bf(f.y) << 16);
        unsigned hi = (unsigned)f2bf(f.z) | ((unsigned)f2bf(f.w) << 16);
        *(uint2*)&As[r * LDK + k4] = make_uint2(lo, hi);
      }
    }
#pragma unroll
    for (int i = 0; i < 4; ++i) {
      int unit = t + i * 256;
      int kp = unit & 31;
      int n4 = (unit >> 5) * 4;
      const float* bp = &Bm[(size_t)(k0 + 2 * kp) * Nn + col0 + n4];
      float4 f0 = *(const float4*)bp;
      float4 f1 = *(const float4*)(bp + Nn);
      *(unsigned*)&Bs[(n4 + 0) * LDK + 2 * kp] =
          (unsigned)f2bf(f0.x) | ((unsigned)f2bf(f1.x) << 16);
      *(unsigned*)&Bs[(n4 + 1) * LDK + 2 * kp] =
          (unsigned)f2bf(f0.y) | ((unsigned)f2bf(f1.y) << 16);
      *(unsigned*)&Bs[(n4 + 2) * LDK + 2 * kp] =
          (unsigned)f2bf(f0.z) | ((unsigned)f2bf(f1.z) << 16);
      *(unsigned*)&Bs[(n4 + 3) * LDK + 2 * kp] =
          (unsigned)f2bf(f0.w) | ((unsigned)f2bf(f1.w) << 16);
    }
    __syncthreads();
#pragma unroll
    for (int ks = 0; ks < 2; ++ks) {
      short8 af[4], bf[4];
#pragma unroll
      for (int m = 0; m < 4; ++m)
        af[m] = *(const short8*)&As[(wrow + m * 16 + lr) * LDK + ks * 32 + lg * 8];
#pragma unroll
      for (int n = 0; n < 4; ++n)
        bf[n] = *(const short8*)&Bs[(wcol + n * 16 + lr) * LDK + ks * 32 + lg * 8];
#pragma unroll
      for (int m = 0; m < 4; ++m)
#pragma unroll
        for (int n = 0; n < 4; ++n)
          acc[m][n] = __builtin_amdgcn_mfma_f32_16x16x32_bf16(
              af[m], bf[n], acc[m][n], 0, 0, 0);
    }
  }
#pragma unroll
  for (int m = 0; m < 4; ++m) {
#pragma unroll
    for (int n = 0; n < 4; ++n) {
      int col = col0 + wcol + n * 16 + lr;
      float badd = bias ? bias[col] : 0.f;
#pragma unroll
      for (int j = 0; j < 4; ++j) {
        int row = row0 + wrow + m * 16 + lg * 4 + j;
        if constexpr (OUTBF16)
          ((unsigned short*)Cp)[(size_t)row * Nn + col] = f2bf(acc[m][n][j] + badd);
        else
          ((float*)Cp)[(size_t)row * Nn + col] = acc[m][n][j] + badd;
      }
    }
  }
}

// ------- 8x8 mean pool: q(bf16)[b,n,c] -> agent(f32)[b,a,c] (b relative) -------
__global__ __launch_bounds__(256) void pool_kernel(const unsigned short* __restrict__ q,
                                                   float* __restrict__ agent) {
  int blk = blockIdx.x;
  int b = blk / kAG, a = blk % kAG;
  int ho = a / 7, wo = a % 7;
  int c = threadIdx.x;
  float s = 0.f;
#pragma unroll
  for (int i = 0; i < 8; ++i) {
    int y = ho * 8 + i;
#pragma unroll
    for (int j = 0; j < 8; ++j) {
      int x = wo * 8 + j;
      s += bf2f(q[((size_t)b * kN + y * kHW + x) * kC + c]);
    }
  }
  agent[((size_t)b * kAG + a) * kC + c] = s * (1.f / 64.f);
}

// ------- abias[h][a][n] = bilin(an)[h,a,n] + ah[h,a,y] + aw[h,a,x] (f32) -------
__global__ __launch_bounds__(256) void abias_kernel(
    const float* __restrict__ an_bias, const float* __restrict__ ah_bias,
    const float* __restrict__ aw_bias, float* __restrict__ abias) {
  int ha = blockIdx.x;  // h*kAG + a
  const float* tab = an_bias + ha * 49;
  const float* ahb = ah_bias + ha * kHW;
  const float* awb = aw_bias + ha * kHW;
  for (int n = threadIdx.x; n < kN; n += 256) {
    int y = n / kHW, x = n % kHW;
    abias[(size_t)ha * kN + n] = bilin7(tab, y, x) + ahb[y] + awb[x];
  }
}

// ------- flash agent attention v2 (bf16 kv), segment pass -------
__global__ __launch_bounds__(256) void agent_attn_flash2_kernel(
    const float* __restrict__ agent, const unsigned short* __restrict__ kv,
    const float* __restrict__ abias, float* __restrict__ part) {
  const int blk = blockIdx.x;
  const int seg = blk % kSEG;
  const int h   = (blk / kSEG) % kH;
  const int b   = blk / (kSEG * kH);
  const int t   = threadIdx.x;
  const int sub = t & 3;        // lane within agent-group: owns n = sub*28+k
  const int g   = t >> 2;       // agent id (g<49 active)
  const bool active = g < kAG;

  __shared__ float KtT[kD][116];            // K transposed, stride 116
  __shared__ float Vt4[kT / 4][kD + 1][4];  // V n-packed: (n,d) -> [n>>2][d][n&3]

  const float scale = 0.17677669529663687f;
  const int segBase = seg * (kT * kTPS);

  float ah[kD];
  if (active) {
    const float* ap = agent + ((size_t)b * kAG + g) * kC + h * kD;
#pragma unroll
    for (int d4 = 0; d4 < 8; ++d4) {
      float4 v = *(const float4*)(ap + d4 * 4);
      ah[d4 * 4 + 0] = v.x; ah[d4 * 4 + 1] = v.y;
      ah[d4 * 4 + 2] = v.z; ah[d4 * 4 + 3] = v.w;
    }
  }
  float accv[kD] = {};
  float lsum = 0.f;

  for (int tile = 0; tile < kTPS; ++tile) {
    const int n0base = segBase + tile * kT;
    __syncthreads();  // protect prior tile's LDS readers
    for (int i = t; i < kT * 4; i += 256) {
      int row = i >> 2, j = i & 3;
      const unsigned short* rp =
          kv + ((size_t)b * kN + n0base + row) * kKV + h * kD + j * 8;
      ushort8 kf = *(const ushort8*)rp;
      ushort8 vf = *(const ushort8*)(rp + kC);
      int nq = row >> 2, e = row & 3;
#pragma unroll
      for (int q8 = 0; q8 < 8; ++q8) {
        KtT[j * 8 + q8][row] = bf2f(kf[q8]);
        Vt4[nq][j * 8 + q8][e] = bf2f(vf[q8]);
      }
    }
    __syncthreads();
    if (active) {
      const float* abp = abias + ((size_t)(h * kAG + g)) * kN + n0base + sub * 28;
#pragma unroll
      for (int k4 = 0; k4 < 7; ++k4) {
        float4 ab = *(const float4*)(abp + k4 * 4);
        float4 dot = {0.f, 0.f, 0.f, 0.f};
#pragma unroll
        for (int dd = 0; dd < kD; ++dd) {
          float a = ah[dd];
          float4 kt = *(const float4*)&KtT[dd][sub * 28 + k4 * 4];
          dot.x = fmaf(a, kt.x, dot.x);
          dot.y = fmaf(a, kt.y, dot.y);
          dot.z = fmaf(a, kt.z, dot.z);
          dot.w = fmaf(a, kt.w, dot.w);
        }
        float p0 = __expf(fmaf(dot.x, scale, ab.x));
        float p1 = __expf(fmaf(dot.y, scale, ab.y));
        float p2 = __expf(fmaf(dot.z, scale, ab.z));
        float p3 = __expf(fmaf(dot.w, scale, ab.w));
        lsum += (p0 + p1) + (p2 + p3);
        const int nq = 7 * sub + k4;
#pragma unroll
        for (int d = 0; d < kD; ++d) {
          const float4 vv = *(const float4*)&Vt4[nq][d][0];
          float s = accv[d];
          s = fmaf(p0, vv.x, s);
          s = fmaf(p1, vv.y, s);
          s = fmaf(p2, vv.z, s);
          s = fmaf(p3, vv.w, s);
          accv[d] = s;
        }
      }
    }
  }
  // cross-lane reduce within 4-lane agent group
#pragma unroll
  for (int d = 0; d < kD; ++d) {
    accv[d] += __shfl_xor(accv[d], 1);
    accv[d] += __shfl_xor(accv[d], 2);
  }
  lsum += __shfl_xor(lsum, 1);
  lsum += __shfl_xor(lsum, 2);
  if (active && sub == 0) {
    float* pb = part + (((size_t)(b * kH + h)) * kSEG + seg) * (kAG * kPART)
              + g * kPART;
    pb[0] = lsum;
#pragma unroll
    for (int d = 0; d < kD; ++d) pb[1 + d] = accv[d];
  }
}

// ------- merge the kSEG flash partials -> agent_v[b,h,a,d] (plain sums) -------
__global__ __launch_bounds__(256) void agent_merge_kernel(
    const float* __restrict__ part, float* __restrict__ agent_v) {
  int g = blockIdx.x * 256 + threadIdx.x;  // over nb*kH*kAG*kD
  int d = g & 31;
  int a = (g >> 5) % kAG;
  int bh = g / (kAG * kD);
  const float* pb = part + (((size_t)bh) * kSEG) * (kAG * kPART) + a * kPART;
  float den = 0.f, num = 0.f;
#pragma unroll
  for (int s = 0; s < kSEG; ++s) {
    const float* p = pb + s * kAG * kPART;
    den += p[0];
    num += p[1 + d];
  }
  agent_v[g] = num / den;
}

// ------- qbias(bf16)[h][a][n] = bilin(na) + ha[y,a] + wa[x,a] -------
__global__ __launch_bounds__(256) void qbias_kernel(
    const float* __restrict__ na_bias, const float* __restrict__ ha_bias,
    const float* __restrict__ wa_bias, unsigned short* __restrict__ qbias) {
  int ha = blockIdx.x;  // h*kAG + a
  int h = ha / kAG, a = ha % kAG;
  const float* tab = na_bias + ha * 49;
  for (int n = threadIdx.x; n < kN; n += 256) {
    int y = n / kHW, x = n % kHW;
    qbias[(size_t)ha * kN + n] = f2bf(bilin7(tab, y, x)
        + ha_bias[(h * kHW + y) * kAG + a]
        + wa_bias[(h * kHW + x) * kAG + a]);
  }
}

// --- q-attention v6: LDS-staged dwc v-tile; bf16 qbias; one thread/(b,h,n) ---
__global__ __launch_bounds__(256) void qattn_v6_kernel(
    unsigned short* __restrict__ q, const unsigned short* __restrict__ kv,
    const float* __restrict__ agent, const float* __restrict__ agent_v,
    const unsigned short* __restrict__ qbias, const float* __restrict__ dwc_w,
    const float* __restrict__ dwc_b) {
  const int h = blockIdx.y, b = blockIdx.z;
  const int t = threadIdx.x;
  const int n0 = blockIdx.x * 256;
  const int n = n0 + t;

  __shared__ float ags[kAG][kD];             // agent[b, a, h*32 : h*32+32]
  __shared__ float avs[kAG][kD];             // agent_v[b, h, a, :]
  __shared__ unsigned short vst[kVROWS][kVSTR];  // v rows n0-58 .. n0+313 (bf16)

  {
    const float4* avsrc = (const float4*)(agent_v + ((size_t)b * kH + h) * kAG * kD);
    for (int i = t; i < 392; i += 256) {
      int a = i >> 3, j = i & 7;
      *(float4*)&avs[a][j * 4] = avsrc[i];
      *(float4*)&ags[a][j * 4] =
          *(const float4*)(agent + ((size_t)b * kAG + a) * kC + h * kD + j * 4);
    }
    // stage dwc v-tile (zero-fill rows outside [0, kN))
    for (int i = t; i < kVROWS * 4; i += 256) {
      int row = i >> 2, j = i & 3;
      int g = n0 - 58 + row;
      ushort8 val = (ushort8)0;
      if (g >= 0 && g < kN)
        val = *(const ushort8*)(kv + ((size_t)b * kN + g) * kKV + kC + h * kD + j * 8);
      *(ushort8*)&vst[row][j * 8] = val;
    }
  }
  __syncthreads();
  if (n >= kN) return;

  const float scale = 0.17677669529663687f;
  unsigned short* qp = q + ((size_t)b * kN + n) * kC + h * kD;
  float qr[kD];
#pragma unroll
  for (int d8 = 0; d8 < 4; ++d8) {
    ushort8 v = *(const ushort8*)(qp + d8 * 8);
#pragma unroll
    for (int e = 0; e < 8; ++e) qr[d8 * 8 + e] = bf2f(v[e]);
  }

  const unsigned short* qbb = qbias + (size_t)(h * kAG) * kN + n;  // + a*kN

  float out[kD] = {};
  float lsum = 0.f;
#pragma unroll 7
  for (int a = 0; a < kAG; ++a) {
    float s = 0.f;
#pragma unroll
    for (int d4 = 0; d4 < 8; ++d4) {
      float4 ar = *(const float4*)&ags[a][d4 * 4];
      s = fmaf(qr[d4 * 4 + 0], ar.x, s);
      s = fmaf(qr[d4 * 4 + 1], ar.y, s);
      s = fmaf(qr[d4 * 4 + 2], ar.z, s);
      s = fmaf(qr[d4 * 4 + 3], ar.w, s);
    }
    float p = __expf(fmaf(s, scale, bf2f(qbb[(size_t)a * kN])));
    lsum += p;
#pragma unroll
    for (int d4 = 0; d4 < 8; ++d4) {
      float4 vr = *(const float4*)&avs[a][d4 * 4];
      out[d4 * 4 + 0] = fmaf(p, vr.x, out[d4 * 4 + 0]);
      out[d4 * 4 + 1] = fmaf(p, vr.y, out[d4 * 4 + 1]);
      out[d4 * 4 + 2] = fmaf(p, vr.z, out[d4 * 4 + 2]);
      out[d4 * 4 + 3] = fmaf(p, vr.w, out[d4 * 4 + 3]);
    }
  }
  float inv = 1.f / lsum;
#pragma unroll
  for (int d = 0; d < kD; ++d) out[d] *= inv;

  // depthwise 3x3 conv from the LDS v-tile (+ bias)
  const float* wb = dwc_w + (h * kD) * 9;   // + d*9 + tap
  const float* bb = dwc_b + h * kD;
#pragma unroll
  for (int d = 0; d < kD; ++d) out[d] += bb[d];
  const int x = n % kHW;
#pragma unroll
  for (int ky = 0; ky < 3; ++ky) {
#pragma unroll
    for (int kx = 0; kx < 3; ++kx) {
      int lrow = t + 58 + (ky - 1) * kHW + (kx - 1);
      int xx = x + kx - 1;
      bool ok = (xx >= 0) && (xx < kHW);
      // yy-out-of-range taps are either zero-filled rows or killed by xx pred.
#pragma unroll
      for (int d8 = 0; d8 < 4; ++d8) {
        ushort8 vv = *(const ushort8*)&vst[lrow][d8 * 8];
#pragma unroll
        for (int e = 0; e < 8; ++e) {
          float vf = ok ? bf2f(vv[e]) : 0.f;
          out[d8 * 8 + e] = fmaf(wb[(d8 * 8 + e) * 9 + ky * 3 + kx], vf,
                                 out[d8 * 8 + e]);
        }
      }
    }
  }
  // in-place store over this thread's own q slice (bf16)
#pragma unroll
  for (int d8 = 0; d8 < 4; ++d8) {
    ushort8 v;
#pragma unroll
    for (int e = 0; e < 8; ++e) v[e] = f2bf(out[d8 * 8 + e]);
    *(ushort8*)(qp + d8 * 8) = v;
  }
}

extern "C" void kernel_launch(void* const* d_in, const int* in_sizes, int n_in,
                              void* d_out, int out_size, void* d_ws, size_t ws_size,
                              hipStream_t stream) {
  const float* x_f     = (const float*)d_in[0];
  const float* x_t     = (const float*)d_in[1];
  const float* Wq      = (const float*)d_in[2];
  const float* Wkv     = (const float*)d_in[3];
  const float* Wproj   = (const float*)d_in[4];
  const float* bproj   = (const float*)d_in[5];
  const float* dwc_w   = (const float*)d_in[6];
  const float* dwc_b   = (const float*)d_in[7];
  const float* an_bias = (const float*)d_in[8];
  const float* na_bias = (const float*)d_in[9];
  const float* ah_bias = (const float*)d_in[10];
  const float* aw_bias = (const float*)d_in[11];
  const float* ha_bias = (const float*)d_in[12];
  const float* wa_bias = (const float*)d_in[13];
  float* out           = (float*)d_out;  // reference output dtype is float32

  const size_t qbiasN = (size_t)kH * kAG * kN;  // elements per table
  // per-batch bytes: q(bf16) + kv(bf16) + agent + agent_v + partials (f32)
  const size_t perbB = (size_t)kN * kC * 2 + (size_t)kN * kKV * 2
                     + ((size_t)kAG * kC + (size_t)kH * kAG * kD
                        + (size_t)kH * kSEG * kAG * kPART) * 4;
  const size_t tabB = qbiasN * 2 + qbiasN * 4;  // qbias bf16 + abias f32
  if (ws_size < tabB) return;
  size_t fit = (ws_size - tabB) / perbB;
  int chunk = (int)(fit < 16 ? fit : 16);
  if (chunk < 1) return;

  char* p = (char*)d_ws;
  unsigned short* qbias = (unsigned short*)p;  p += qbiasN * 2;
  float* abias = (float*)p;                    p += qbiasN * 4;
  unsigned short* q  = (unsigned short*)p;     p += (size_t)chunk * kN * kC * 2;
  unsigned short* kv = (unsigned short*)p;     p += (size_t)chunk * kN * kKV * 2;
  float* agent  = (float*)p;                   p += (size_t)chunk * kAG * kC * 4;
  float* agentv = (float*)p;                   p += (size_t)chunk * kH * kAG * kD * 4;
  float* part   = (float*)p;

  qbias_kernel<<<kH * kAG, 256, 0, stream>>>(na_bias, ha_bias, wa_bias, qbias);
  abias_kernel<<<kH * kAG, 256, 0, stream>>>(an_bias, ah_bias, aw_bias, abias);

  for (int b0 = 0; b0 < kB; b0 += chunk) {
    int nb = (kB - b0) < chunk ? (kB - b0) : chunk;
    const int M = nb * kN;
    const float* xf_c = x_f + (size_t)b0 * kN * kC;
    const float* xt_c = x_t + (size_t)b0 * kN * kC;
    float* out_c = out + (size_t)b0 * kN * kC;

    gemm_mixed_kernel<false, true><<<dim3(kC / BN, M / BM), 256, 0, stream>>>(
        xf_c, Wq, nullptr, q, M, kC, kC);
    gemm_mixed_kernel<false, true><<<dim3(kKV / BN, M / BM), 256, 0, stream>>>(
        xt_c, Wkv, nullptr, kv, M, kKV, kC);
    pool_kernel<<<nb * kAG, 256, 0, stream>>>(q, agent);
    agent_attn_flash2_kernel<<<nb * kH * kSEG, 256, 0, stream>>>(agent, kv, abias, part);
    agent_merge_kernel<<<nb * kAG, 256, 0, stream>>>(part, agentv);
    qattn_v6_kernel<<<dim3((kN + 255) / 256, kH, nb), 256, 0, stream>>>(
        q, kv, agent, agentv, qbias, dwc_w, dwc_b);
    gemm_mixed_kernel<true, false><<<dim3(kC / BN, M / BM), 256, 0, stream>>>(
        q, Wproj, bproj, out_c, M, kC, kC);
  }
}

// Round 13
// 374.927 us; speedup vs baseline: 1.0801x; 1.0801x over previous
//
#include <hip/hip_runtime.h>
#include <hip/hip_bf16.h>

namespace {
constexpr int kB  = 16;
constexpr int kN  = 3136;
constexpr int kC  = 256;
constexpr int kH  = 8;     // heads
constexpr int kD  = 32;    // head dim
constexpr int kAG = 49;    // agents
constexpr int kHW = 56;
constexpr int kKV = 512;   // kv row stride (k cols 0..255, v cols 256..511)
constexpr int kT   = 112;  // flash tile (2 image rows)
constexpr int kSEG = 7;    // n-segments per (b,h)
constexpr int kTPS = kN / (kT * kSEG);  // 4 tiles per segment
constexpr int kPART = 33;  // per (b,h,seg,a): l, acc[32]

constexpr int BM = 128, BN = 128, BK = 64;
constexpr int LDK = BK + 8;   // bf16 row stride 72 (144 B)

constexpr int kNT = kN / 256 + 1;  // 13 n-tiles per (b,h)
}

typedef __attribute__((ext_vector_type(8))) short short8;
typedef __attribute__((ext_vector_type(8))) unsigned short ushort8;
typedef __attribute__((ext_vector_type(4))) float f32x4;

__device__ __forceinline__ unsigned short f2bf(float f) {
  union { float f; unsigned u; } v; v.f = f;
  unsigned r = (v.u + 0x7FFF + ((v.u >> 16) & 1)) >> 16;  // RNE
  return (unsigned short)r;
}
__device__ __forceinline__ float bf2f(unsigned short u) {
  union { unsigned u; float f; } v; v.u = ((unsigned)u) << 16;
  return v.f;
}

__device__ __forceinline__ float bilin7(const float* __restrict__ tab, int y, int x) {
  // jax.image.resize (7,7)->(56,56) bilinear, half-pixel centers, edge clamp.
  float fy = (y + 0.5f) * 0.125f - 0.5f;
  float fx = (x + 0.5f) * 0.125f - 0.5f;
  float fy0 = floorf(fy), fx0 = floorf(fx);
  float wy = fy - fy0, wx = fx - fx0;
  int y0 = (int)fy0, x0 = (int)fx0;
  int y0c = min(6, max(0, y0)),     x0c = min(6, max(0, x0));
  int y1c = min(6, max(0, y0 + 1)), x1c = min(6, max(0, x0 + 1));
  float v00 = tab[y0c * 7 + x0c], v01 = tab[y0c * 7 + x1c];
  float v10 = tab[y1c * 7 + x0c], v11 = tab[y1c * 7 + x1c];
  float top = v00 + wx * (v01 - v00);
  float bot = v10 + wx * (v11 - v10);
  return top + wy * (bot - top);
}

// ---- bf16-MFMA GEMM: C = A @ B (+bias). A f32 or bf16; C f32 or bf16. ----
template <bool ABF16, bool OUTBF16>
__global__ __launch_bounds__(256) void gemm_mixed_kernel(
    const void* __restrict__ Ap, const float* __restrict__ Bm,
    const float* __restrict__ bias, void* __restrict__ Cp,
    int M, int Nn, int K) {
  __shared__ unsigned short As[BM * LDK];
  __shared__ unsigned short Bs[BN * LDK];
  const int t = threadIdx.x;

  int tx = blockIdx.x, ty = blockIdx.y;
  {
    int nwg = gridDim.x * gridDim.y;
    if ((nwg & 7) == 0) {
      int bid = ty * gridDim.x + tx;
      int per8 = nwg >> 3;
      int lt = (bid & 7) * per8 + (bid >> 3);
      tx = lt % gridDim.x;
      ty = lt / gridDim.x;
    }
  }
  const int row0 = ty * BM;
  const int col0 = tx * BN;
  const int lane = t & 63;
  const int wid  = t >> 6;
  const int wrow = (wid >> 1) * 64;
  const int wcol = (wid & 1) * 64;
  const int lr = lane & 15, lg = lane >> 4;

  f32x4 acc[4][4] = {};

  for (int k0 = 0; k0 < K; k0 += BK) {
    __syncthreads();
    if constexpr (ABF16) {
      const unsigned short* A = (const unsigned short*)Ap;
#pragma unroll
      for (int i = 0; i < 4; ++i) {
        int idx = t + i * 256;
        int r = idx >> 3, k8 = (idx & 7) * 8;
        *(ushort8*)&As[r * LDK + k8] =
            *(const ushort8*)&A[(size_t)(row0 + r) * K + k0 + k8];
      }
    } else {
      const float* A = (const float*)Ap;
#pragma unroll
      for (int i = 0; i < 8; ++i) {
        int idx = t + i * 256;
        int r = idx >> 4, k4 = (idx & 15) * 4;
        float4 f = *(const float4*)&A[(size_t)(row0 + r) * K + k0 + k4];
        unsigned lo = (unsigned)f2bf(f.x) | ((unsigned)f2bf(f.y) << 16);
        unsigned hi = (unsigned)f2bf(f.z) | ((unsigned)f2bf(f.w) << 16);
        *(uint2*)&As[r * LDK + k4] = make_uint2(lo, hi);
      }
    }
#pragma unroll
    for (int i = 0; i < 4; ++i) {
      int unit = t + i * 256;
      int kp = unit & 31;
      int n4 = (unit >> 5) * 4;
      const float* bp = &Bm[(size_t)(k0 + 2 * kp) * Nn + col0 + n4];
      float4 f0 = *(const float4*)bp;
      float4 f1 = *(const float4*)(bp + Nn);
      *(unsigned*)&Bs[(n4 + 0) * LDK + 2 * kp] =
          (unsigned)f2bf(f0.x) | ((unsigned)f2bf(f1.x) << 16);
      *(unsigned*)&Bs[(n4 + 1) * LDK + 2 * kp] =
          (unsigned)f2bf(f0.y) | ((unsigned)f2bf(f1.y) << 16);
      *(unsigned*)&Bs[(n4 + 2) * LDK + 2 * kp] =
          (unsigned)f2bf(f0.z) | ((unsigned)f2bf(f1.z) << 16);
      *(unsigned*)&Bs[(n4 + 3) * LDK + 2 * kp] =
          (unsigned)f2bf(f0.w) | ((unsigned)f2bf(f1.w) << 16);
    }
    __syncthreads();
#pragma unroll
    for (int ks = 0; ks < 2; ++ks) {
      short8 af[4], bf[4];
#pragma unroll
      for (int m = 0; m < 4; ++m)
        af[m] = *(const short8*)&As[(wrow + m * 16 + lr) * LDK + ks * 32 + lg * 8];
#pragma unroll
      for (int n = 0; n < 4; ++n)
        bf[n] = *(const short8*)&Bs[(wcol + n * 16 + lr) * LDK + ks * 32 + lg * 8];
#pragma unroll
      for (int m = 0; m < 4; ++m)
#pragma unroll
        for (int n = 0; n < 4; ++n)
          acc[m][n] = __builtin_amdgcn_mfma_f32_16x16x32_bf16(
              af[m], bf[n], acc[m][n], 0, 0, 0);
    }
  }
#pragma unroll
  for (int m = 0; m < 4; ++m) {
#pragma unroll
    for (int n = 0; n < 4; ++n) {
      int col = col0 + wcol + n * 16 + lr;
      float badd = bias ? bias[col] : 0.f;
#pragma unroll
      for (int j = 0; j < 4; ++j) {
        int row = row0 + wrow + m * 16 + lg * 4 + j;
        if constexpr (OUTBF16)
          ((unsigned short*)Cp)[(size_t)row * Nn + col] = f2bf(acc[m][n][j] + badd);
        else
          ((float*)Cp)[(size_t)row * Nn + col] = acc[m][n][j] + badd;
      }
    }
  }
}

// ------- 8x8 mean pool: q(bf16)[b,n,c] -> agent(f32)[b,a,c] (b relative) -------
__global__ __launch_bounds__(256) void pool_kernel(const unsigned short* __restrict__ q,
                                                   float* __restrict__ agent) {
  int blk = blockIdx.x;
  int b = blk / kAG, a = blk % kAG;
  int ho = a / 7, wo = a % 7;
  int c = threadIdx.x;
  float s = 0.f;
#pragma unroll
  for (int i = 0; i < 8; ++i) {
    int y = ho * 8 + i;
#pragma unroll
    for (int j = 0; j < 8; ++j) {
      int x = wo * 8 + j;
      s += bf2f(q[((size_t)b * kN + y * kHW + x) * kC + c]);
    }
  }
  agent[((size_t)b * kAG + a) * kC + c] = s * (1.f / 64.f);
}

// ------- abias[h][a][n] = bilin(an)[h,a,n] + ah[h,a,y] + aw[h,a,x] (f32) -------
__global__ __launch_bounds__(256) void abias_kernel(
    const float* __restrict__ an_bias, const float* __restrict__ ah_bias,
    const float* __restrict__ aw_bias, float* __restrict__ abias) {
  int ha = blockIdx.x;  // h*kAG + a
  const float* tab = an_bias + ha * 49;
  const float* ahb = ah_bias + ha * kHW;
  const float* awb = aw_bias + ha * kHW;
  for (int n = threadIdx.x; n < kN; n += 256) {
    int y = n / kHW, x = n % kHW;
    abias[(size_t)ha * kN + n] = bilin7(tab, y, x) + ahb[y] + awb[x];
  }
}

// ------- flash agent attention v2 (bf16 kv), segment pass -------
__global__ __launch_bounds__(256) void agent_attn_flash2_kernel(
    const float* __restrict__ agent, const unsigned short* __restrict__ kv,
    const float* __restrict__ abias, float* __restrict__ part) {
  const int blk = blockIdx.x;
  const int seg = blk % kSEG;
  const int h   = (blk / kSEG) % kH;
  const int b   = blk / (kSEG * kH);
  const int t   = threadIdx.x;
  const int sub = t & 3;        // lane within agent-group: owns n = sub*28+k
  const int g   = t >> 2;       // agent id (g<49 active)
  const bool active = g < kAG;

  __shared__ float KtT[kD][116];            // K transposed, stride 116
  __shared__ float Vt4[kT / 4][kD + 1][4];  // V n-packed: (n,d) -> [n>>2][d][n&3]

  const float scale = 0.17677669529663687f;
  const int segBase = seg * (kT * kTPS);

  float ah[kD];
  if (active) {
    const float* ap = agent + ((size_t)b * kAG + g) * kC + h * kD;
#pragma unroll
    for (int d4 = 0; d4 < 8; ++d4) {
      float4 v = *(const float4*)(ap + d4 * 4);
      ah[d4 * 4 + 0] = v.x; ah[d4 * 4 + 1] = v.y;
      ah[d4 * 4 + 2] = v.z; ah[d4 * 4 + 3] = v.w;
    }
  }
  float accv[kD] = {};
  float lsum = 0.f;

  for (int tile = 0; tile < kTPS; ++tile) {
    const int n0base = segBase + tile * kT;
    __syncthreads();  // protect prior tile's LDS readers
    for (int i = t; i < kT * 4; i += 256) {
      int row = i >> 2, j = i & 3;
      const unsigned short* rp =
          kv + ((size_t)b * kN + n0base + row) * kKV + h * kD + j * 8;
      ushort8 kf = *(const ushort8*)rp;
      ushort8 vf = *(const ushort8*)(rp + kC);
      int nq = row >> 2, e = row & 3;
#pragma unroll
      for (int q8 = 0; q8 < 8; ++q8) {
        KtT[j * 8 + q8][row] = bf2f(kf[q8]);
        Vt4[nq][j * 8 + q8][e] = bf2f(vf[q8]);
      }
    }
    __syncthreads();
    if (active) {
      const float* abp = abias + ((size_t)(h * kAG + g)) * kN + n0base + sub * 28;
#pragma unroll
      for (int k4 = 0; k4 < 7; ++k4) {
        float4 ab = *(const float4*)(abp + k4 * 4);
        float4 dot = {0.f, 0.f, 0.f, 0.f};
#pragma unroll
        for (int dd = 0; dd < kD; ++dd) {
          float a = ah[dd];
          float4 kt = *(const float4*)&KtT[dd][sub * 28 + k4 * 4];
          dot.x = fmaf(a, kt.x, dot.x);
          dot.y = fmaf(a, kt.y, dot.y);
          dot.z = fmaf(a, kt.z, dot.z);
          dot.w = fmaf(a, kt.w, dot.w);
        }
        float p0 = __expf(fmaf(dot.x, scale, ab.x));
        float p1 = __expf(fmaf(dot.y, scale, ab.y));
        float p2 = __expf(fmaf(dot.z, scale, ab.z));
        float p3 = __expf(fmaf(dot.w, scale, ab.w));
        lsum += (p0 + p1) + (p2 + p3);
        const int nq = 7 * sub + k4;
#pragma unroll
        for (int d = 0; d < kD; ++d) {
          const float4 vv = *(const float4*)&Vt4[nq][d][0];
          float s = accv[d];
          s = fmaf(p0, vv.x, s);
          s = fmaf(p1, vv.y, s);
          s = fmaf(p2, vv.z, s);
          s = fmaf(p3, vv.w, s);
          accv[d] = s;
        }
      }
    }
  }
  // cross-lane reduce within 4-lane agent group
#pragma unroll
  for (int d = 0; d < kD; ++d) {
    accv[d] += __shfl_xor(accv[d], 1);
    accv[d] += __shfl_xor(accv[d], 2);
  }
  lsum += __shfl_xor(lsum, 1);
  lsum += __shfl_xor(lsum, 2);
  if (active && sub == 0) {
    float* pb = part + (((size_t)(b * kH + h)) * kSEG + seg) * (kAG * kPART)
              + g * kPART;
    pb[0] = lsum;
#pragma unroll
    for (int d = 0; d < kD; ++d) pb[1 + d] = accv[d];
  }
}

// ------- merge the kSEG flash partials -> agent_v[b,h,a,d] (plain sums) -------
__global__ __launch_bounds__(256) void agent_merge_kernel(
    const float* __restrict__ part, float* __restrict__ agent_v) {
  int g = blockIdx.x * 256 + threadIdx.x;  // over nb*kH*kAG*kD
  int d = g & 31;
  int a = (g >> 5) % kAG;
  int bh = g / (kAG * kD);
  const float* pb = part + (((size_t)bh) * kSEG) * (kAG * kPART) + a * kPART;
  float den = 0.f, num = 0.f;
#pragma unroll
  for (int s = 0; s < kSEG; ++s) {
    const float* p = pb + s * kAG * kPART;
    den += p[0];
    num += p[1 + d];
  }
  agent_v[g] = num / den;
}

// ------- qbias(bf16)[h][a][n] = bilin(na) + ha[y,a] + wa[x,a] -------
__global__ __launch_bounds__(256) void qbias_kernel(
    const float* __restrict__ na_bias, const float* __restrict__ ha_bias,
    const float* __restrict__ wa_bias, unsigned short* __restrict__ qbias) {
  int ha = blockIdx.x;  // h*kAG + a
  int h = ha / kAG, a = ha % kAG;
  const float* tab = na_bias + ha * 49;
  for (int n = threadIdx.x; n < kN; n += 256) {
    int y = n / kHW, x = n % kHW;
    qbias[(size_t)ha * kN + n] = f2bf(bilin7(tab, y, x)
        + ha_bias[(h * kHW + y) * kAG + a]
        + wa_bias[(h * kHW + x) * kAG + a]);
  }
}

// --- q-attention v7: v5 body + h->XCD locality swizzle; one thread/(b,h,n) ---
// Linearized dispatch id -> h = lin & 7 (same-h blocks round-robin to one XCD;
// per-head working set qbias 307KB + v-slices 3.2MB fits the 4MB XCD L2).
__global__ __launch_bounds__(256) void qattn_v7_kernel(
    unsigned short* __restrict__ q, const unsigned short* __restrict__ kv,
    const float* __restrict__ agent, const float* __restrict__ agent_v,
    const unsigned short* __restrict__ qbias, const float* __restrict__ dwc_w,
    const float* __restrict__ dwc_b, int nb) {
  const int t = threadIdx.x;
  int lin = blockIdx.x + gridDim.x * (blockIdx.y + gridDim.y * blockIdx.z);
  const int h   = lin & 7;
  int rest = lin >> 3;                 // [0, kNT*nb)
  const int n0 = (rest % kNT) * 256;
  const int b  = rest / kNT;
  const int n = n0 + t;

  __shared__ float ags[kAG][kD];   // agent[b, a, h*32 : h*32+32]
  __shared__ float avs[kAG][kD];   // agent_v[b, h, a, :]

  {
    const float4* avsrc = (const float4*)(agent_v + ((size_t)b * kH + h) * kAG * kD);
    for (int i = t; i < 392; i += 256) {
      int a = i >> 3, j = i & 7;
      *(float4*)&avs[a][j * 4] = avsrc[i];
      *(float4*)&ags[a][j * 4] =
          *(const float4*)(agent + ((size_t)b * kAG + a) * kC + h * kD + j * 4);
    }
  }
  __syncthreads();
  if (n >= kN) return;

  const float scale = 0.17677669529663687f;
  unsigned short* qp = q + ((size_t)b * kN + n) * kC + h * kD;
  float qr[kD];
#pragma unroll
  for (int d8 = 0; d8 < 4; ++d8) {
    ushort8 v = *(const ushort8*)(qp + d8 * 8);
#pragma unroll
    for (int e = 0; e < 8; ++e) qr[d8 * 8 + e] = bf2f(v[e]);
  }

  const unsigned short* qbb = qbias + (size_t)(h * kAG) * kN + n;  // + a*kN

  float out[kD] = {};
  float lsum = 0.f;
#pragma unroll 7
  for (int a = 0; a < kAG; ++a) {
    float s = 0.f;
#pragma unroll
    for (int d4 = 0; d4 < 8; ++d4) {
      float4 ar = *(const float4*)&ags[a][d4 * 4];
      s = fmaf(qr[d4 * 4 + 0], ar.x, s);
      s = fmaf(qr[d4 * 4 + 1], ar.y, s);
      s = fmaf(qr[d4 * 4 + 2], ar.z, s);
      s = fmaf(qr[d4 * 4 + 3], ar.w, s);
    }
    float p = __expf(fmaf(s, scale, bf2f(qbb[(size_t)a * kN])));
    lsum += p;
#pragma unroll
    for (int d4 = 0; d4 < 8; ++d4) {
      float4 vr = *(const float4*)&avs[a][d4 * 4];
      out[d4 * 4 + 0] = fmaf(p, vr.x, out[d4 * 4 + 0]);
      out[d4 * 4 + 1] = fmaf(p, vr.y, out[d4 * 4 + 1]);
      out[d4 * 4 + 2] = fmaf(p, vr.z, out[d4 * 4 + 2]);
      out[d4 * 4 + 3] = fmaf(p, vr.w, out[d4 * 4 + 3]);
    }
  }
  float inv = 1.f / lsum;
#pragma unroll
  for (int d = 0; d < kD; ++d) out[d] *= inv;

  // depthwise 3x3 conv on v head-slice (+ bias); weights uniform
  const float* wb = dwc_w + (h * kD) * 9;   // + d*9 + tap
  const float* bb = dwc_b + h * kD;
#pragma unroll
  for (int d = 0; d < kD; ++d) out[d] += bb[d];
  const int y = n / kHW, x = n % kHW;
#pragma unroll
  for (int ky = 0; ky < 3; ++ky) {
    int yy = y + ky - 1;
    if (yy < 0 || yy >= kHW) continue;
#pragma unroll
    for (int kx = 0; kx < 3; ++kx) {
      int xx = x + kx - 1;
      if (xx < 0 || xx >= kHW) continue;
      const unsigned short* vp =
          kv + ((size_t)b * kN + yy * kHW + xx) * kKV + kC + h * kD;
#pragma unroll
      for (int d8 = 0; d8 < 4; ++d8) {
        ushort8 vv = *(const ushort8*)(vp + d8 * 8);
#pragma unroll
        for (int e = 0; e < 8; ++e)
          out[d8 * 8 + e] = fmaf(wb[(d8 * 8 + e) * 9 + ky * 3 + kx],
                                 bf2f(vv[e]), out[d8 * 8 + e]);
      }
    }
  }
  // in-place store over this thread's own q slice (bf16)
#pragma unroll
  for (int d8 = 0; d8 < 4; ++d8) {
    ushort8 v;
#pragma unroll
    for (int e = 0; e < 8; ++e) v[e] = f2bf(out[d8 * 8 + e]);
    *(ushort8*)(qp + d8 * 8) = v;
  }
}

extern "C" void kernel_launch(void* const* d_in, const int* in_sizes, int n_in,
                              void* d_out, int out_size, void* d_ws, size_t ws_size,
                              hipStream_t stream) {
  const float* x_f     = (const float*)d_in[0];
  const float* x_t     = (const float*)d_in[1];
  const float* Wq      = (const float*)d_in[2];
  const float* Wkv     = (const float*)d_in[3];
  const float* Wproj   = (const float*)d_in[4];
  const float* bproj   = (const float*)d_in[5];
  const float* dwc_w   = (const float*)d_in[6];
  const float* dwc_b   = (const float*)d_in[7];
  const float* an_bias = (const float*)d_in[8];
  const float* na_bias = (const float*)d_in[9];
  const float* ah_bias = (const float*)d_in[10];
  const float* aw_bias = (const float*)d_in[11];
  const float* ha_bias = (const float*)d_in[12];
  const float* wa_bias = (const float*)d_in[13];
  float* out           = (float*)d_out;  // reference output dtype is float32

  const size_t qbiasN = (size_t)kH * kAG * kN;  // elements per table
  const size_t perbB = (size_t)kN * kC * 2 + (size_t)kN * kKV * 2
                     + ((size_t)kAG * kC + (size_t)kH * kAG * kD
                        + (size_t)kH * kSEG * kAG * kPART) * 4;
  const size_t tabB = qbiasN * 2 + qbiasN * 4;  // qbias bf16 + abias f32
  if (ws_size < tabB) return;
  size_t fit = (ws_size - tabB) / perbB;
  int chunk = (int)(fit < 16 ? fit : 16);
  if (chunk < 1) return;

  char* p = (char*)d_ws;
  unsigned short* qbias = (unsigned short*)p;  p += qbiasN * 2;
  float* abias = (float*)p;                    p += qbiasN * 4;
  unsigned short* q  = (unsigned short*)p;     p += (size_t)chunk * kN * kC * 2;
  unsigned short* kv = (unsigned short*)p;     p += (size_t)chunk * kN * kKV * 2;
  float* agent  = (float*)p;                   p += (size_t)chunk * kAG * kC * 4;
  float* agentv = (float*)p;                   p += (size_t)chunk * kH * kAG * kD * 4;
  float* part   = (float*)p;

  qbias_kernel<<<kH * kAG, 256, 0, stream>>>(na_bias, ha_bias, wa_bias, qbias);
  abias_kernel<<<kH * kAG, 256, 0, stream>>>(an_bias, ah_bias, aw_bias, abias);

  for (int b0 = 0; b0 < kB; b0 += chunk) {
    int nb = (kB - b0) < chunk ? (kB - b0) : chunk;
    const int M = nb * kN;
    const float* xf_c = x_f + (size_t)b0 * kN * kC;
    const float* xt_c = x_t + (size_t)b0 * kN * kC;
    float* out_c = out + (size_t)b0 * kN * kC;

    gemm_mixed_kernel<false, true><<<dim3(kC / BN, M / BM), 256, 0, stream>>>(
        xf_c, Wq, nullptr, q, M, kC, kC);
    gemm_mixed_kernel<false, true><<<dim3(kKV / BN, M / BM), 256, 0, stream>>>(
        xt_c, Wkv, nullptr, kv, M, kKV, kC);
    pool_kernel<<<nb * kAG, 256, 0, stream>>>(q, agent);
    agent_attn_flash2_kernel<<<nb * kH * kSEG, 256, 0, stream>>>(agent, kv, abias, part);
    agent_merge_kernel<<<nb * kAG, 256, 0, stream>>>(part, agentv);
    qattn_v7_kernel<<<dim3(kNT, kH, nb), 256, 0, stream>>>(
        q, kv, agent, agentv, qbias, dwc_w, dwc_b, nb);
    gemm_mixed_kernel<true, false><<<dim3(kC / BN, M / BM), 256, 0, stream>>>(
        q, Wproj, bproj, out_c, M, kC, kC);
  }
}

// Round 14
// 335.954 us; speedup vs baseline: 1.2054x; 1.1160x over previous
//
#include <hip/hip_runtime.h>
#include <hip/hip_bf16.h>

namespace {
constexpr int kB  = 16;
constexpr int kN  = 3136;
constexpr int kC  = 256;
constexpr int kH  = 8;     // heads
constexpr int kD  = 32;    // head dim
constexpr int kAG = 49;    // agents
constexpr int kHW = 56;
constexpr int kKV = 512;   // kv row stride (k cols 0..255, v cols 256..511)
constexpr int kT   = 112;  // flash tile (2 image rows)
constexpr int kSEG = 7;    // n-segments per (b,h)
constexpr int kTPS = kN / (kT * kSEG);  // 4 tiles per segment
constexpr int kPART = 33;  // per (b,h,seg,a): l, acc[32]

constexpr int BM = 128, BN = 128, BK = 64;
constexpr int LDK = BK + 8;   // bf16 row stride 72 (144 B)

constexpr int kNT = kN / 256 + 1;  // 13 n-tiles per (b,h)
}

typedef __attribute__((ext_vector_type(8))) short short8;
typedef __attribute__((ext_vector_type(8))) unsigned short ushort8;
typedef __attribute__((ext_vector_type(4))) float f32x4;

__device__ __forceinline__ unsigned short f2bf(float f) {
  union { float f; unsigned u; } v; v.f = f;
  unsigned r = (v.u + 0x7FFF + ((v.u >> 16) & 1)) >> 16;  // RNE
  return (unsigned short)r;
}
__device__ __forceinline__ float bf2f(unsigned short u) {
  union { unsigned u; float f; } v; v.u = ((unsigned)u) << 16;
  return v.f;
}

__device__ __forceinline__ float bilin7(const float* __restrict__ tab, int y, int x) {
  // jax.image.resize (7,7)->(56,56) bilinear, half-pixel centers, edge clamp.
  float fy = (y + 0.5f) * 0.125f - 0.5f;
  float fx = (x + 0.5f) * 0.125f - 0.5f;
  float fy0 = floorf(fy), fx0 = floorf(fx);
  float wy = fy - fy0, wx = fx - fx0;
  int y0 = (int)fy0, x0 = (int)fx0;
  int y0c = min(6, max(0, y0)),     x0c = min(6, max(0, x0));
  int y1c = min(6, max(0, y0 + 1)), x1c = min(6, max(0, x0 + 1));
  float v00 = tab[y0c * 7 + x0c], v01 = tab[y0c * 7 + x1c];
  float v10 = tab[y1c * 7 + x0c], v11 = tab[y1c * 7 + x1c];
  float top = v00 + wx * (v01 - v00);
  float bot = v10 + wx * (v11 - v10);
  return top + wy * (bot - top);
}

// ---- bf16-MFMA GEMM: C = A @ B (+bias). A f32 or bf16; C f32 or bf16. ----
template <bool ABF16, bool OUTBF16>
__global__ __launch_bounds__(256) void gemm_mixed_kernel(
    const void* __restrict__ Ap, const float* __restrict__ Bm,
    const float* __restrict__ bias, void* __restrict__ Cp,
    int M, int Nn, int K) {
  __shared__ unsigned short As[BM * LDK];
  __shared__ unsigned short Bs[BN * LDK];
  const int t = threadIdx.x;

  int tx = blockIdx.x, ty = blockIdx.y;
  {
    int nwg = gridDim.x * gridDim.y;
    if ((nwg & 7) == 0) {
      int bid = ty * gridDim.x + tx;
      int per8 = nwg >> 3;
      int lt = (bid & 7) * per8 + (bid >> 3);
      tx = lt % gridDim.x;
      ty = lt / gridDim.x;
    }
  }
  const int row0 = ty * BM;
  const int col0 = tx * BN;
  const int lane = t & 63;
  const int wid  = t >> 6;
  const int wrow = (wid >> 1) * 64;
  const int wcol = (wid & 1) * 64;
  const int lr = lane & 15, lg = lane >> 4;

  f32x4 acc[4][4] = {};

  for (int k0 = 0; k0 < K; k0 += BK) {
    __syncthreads();
    if constexpr (ABF16) {
      const unsigned short* A = (const unsigned short*)Ap;
#pragma unroll
      for (int i = 0; i < 4; ++i) {
        int idx = t + i * 256;
        int r = idx >> 3, k8 = (idx & 7) * 8;
        *(ushort8*)&As[r * LDK + k8] =
            *(const ushort8*)&A[(size_t)(row0 + r) * K + k0 + k8];
      }
    } else {
      const float* A = (const float*)Ap;
#pragma unroll
      for (int i = 0; i < 8; ++i) {
        int idx = t + i * 256;
        int r = idx >> 4, k4 = (idx & 15) * 4;
        float4 f = *(const float4*)&A[(size_t)(row0 + r) * K + k0 + k4];
        unsigned lo = (unsigned)f2bf(f.x) | ((unsigned)f2bf(f.y) << 16);
        unsigned hi = (unsigned)f2bf(f.z) | ((unsigned)f2bf(f.w) << 16);
        *(uint2*)&As[r * LDK + k4] = make_uint2(lo, hi);
      }
    }
#pragma unroll
    for (int i = 0; i < 4; ++i) {
      int unit = t + i * 256;
      int kp = unit & 31;
      int n4 = (unit >> 5) * 4;
      const float* bp = &Bm[(size_t)(k0 + 2 * kp) * Nn + col0 + n4];
      float4 f0 = *(const float4*)bp;
      float4 f1 = *(const float4*)(bp + Nn);
      *(unsigned*)&Bs[(n4 + 0) * LDK + 2 * kp] =
          (unsigned)f2bf(f0.x) | ((unsigned)f2bf(f1.x) << 16);
      *(unsigned*)&Bs[(n4 + 1) * LDK + 2 * kp] =
          (unsigned)f2bf(f0.y) | ((unsigned)f2bf(f1.y) << 16);
      *(unsigned*)&Bs[(n4 + 2) * LDK + 2 * kp] =
          (unsigned)f2bf(f0.z) | ((unsigned)f2bf(f1.z) << 16);
      *(unsigned*)&Bs[(n4 + 3) * LDK + 2 * kp] =
          (unsigned)f2bf(f0.w) | ((unsigned)f2bf(f1.w) << 16);
    }
    __syncthreads();
#pragma unroll
    for (int ks = 0; ks < 2; ++ks) {
      short8 af[4], bf[4];
#pragma unroll
      for (int m = 0; m < 4; ++m)
        af[m] = *(const short8*)&As[(wrow + m * 16 + lr) * LDK + ks * 32 + lg * 8];
#pragma unroll
      for (int n = 0; n < 4; ++n)
        bf[n] = *(const short8*)&Bs[(wcol + n * 16 + lr) * LDK + ks * 32 + lg * 8];
#pragma unroll
      for (int m = 0; m < 4; ++m)
#pragma unroll
        for (int n = 0; n < 4; ++n)
          acc[m][n] = __builtin_amdgcn_mfma_f32_16x16x32_bf16(
              af[m], bf[n], acc[m][n], 0, 0, 0);
    }
  }
#pragma unroll
  for (int m = 0; m < 4; ++m) {
#pragma unroll
    for (int n = 0; n < 4; ++n) {
      int col = col0 + wcol + n * 16 + lr;
      float badd = bias ? bias[col] : 0.f;
#pragma unroll
      for (int j = 0; j < 4; ++j) {
        int row = row0 + wrow + m * 16 + lg * 4 + j;
        if constexpr (OUTBF16)
          ((unsigned short*)Cp)[(size_t)row * Nn + col] = f2bf(acc[m][n][j] + badd);
        else
          ((float*)Cp)[(size_t)row * Nn + col] = acc[m][n][j] + badd;
      }
    }
  }
}

// ------- 8x8 mean pool: q(bf16)[b,n,c] -> agent(f32)[b,a,c] (b relative) -------
__global__ __launch_bounds__(256) void pool_kernel(const unsigned short* __restrict__ q,
                                                   float* __restrict__ agent) {
  int blk = blockIdx.x;
  int b = blk / kAG, a = blk % kAG;
  int ho = a / 7, wo = a % 7;
  int c = threadIdx.x;
  float s = 0.f;
#pragma unroll
  for (int i = 0; i < 8; ++i) {
    int y = ho * 8 + i;
#pragma unroll
    for (int j = 0; j < 8; ++j) {
      int x = wo * 8 + j;
      s += bf2f(q[((size_t)b * kN + y * kHW + x) * kC + c]);
    }
  }
  agent[((size_t)b * kAG + a) * kC + c] = s * (1.f / 64.f);
}

// ------- abias[h][a][n] = bilin(an)[h,a,n] + ah[h,a,y] + aw[h,a,x] (f32) -------
__global__ __launch_bounds__(256) void abias_kernel(
    const float* __restrict__ an_bias, const float* __restrict__ ah_bias,
    const float* __restrict__ aw_bias, float* __restrict__ abias) {
  int ha = blockIdx.x;  // h*kAG + a
  const float* tab = an_bias + ha * 49;
  const float* ahb = ah_bias + ha * kHW;
  const float* awb = aw_bias + ha * kHW;
  for (int n = threadIdx.x; n < kN; n += 256) {
    int y = n / kHW, x = n % kHW;
    abias[(size_t)ha * kN + n] = bilin7(tab, y, x) + ahb[y] + awb[x];
  }
}

// ------- flash agent attention v2 (bf16 kv), segment pass -------
__global__ __launch_bounds__(256) void agent_attn_flash2_kernel(
    const float* __restrict__ agent, const unsigned short* __restrict__ kv,
    const float* __restrict__ abias, float* __restrict__ part) {
  const int blk = blockIdx.x;
  const int seg = blk % kSEG;
  const int h   = (blk / kSEG) % kH;
  const int b   = blk / (kSEG * kH);
  const int t   = threadIdx.x;
  const int sub = t & 3;        // lane within agent-group: owns n = sub*28+k
  const int g   = t >> 2;       // agent id (g<49 active)
  const bool active = g < kAG;

  __shared__ float KtT[kD][116];            // K transposed, stride 116
  __shared__ float Vt4[kT / 4][kD + 1][4];  // V n-packed: (n,d) -> [n>>2][d][n&3]

  const float scale = 0.17677669529663687f;
  const int segBase = seg * (kT * kTPS);

  float ah[kD];
  if (active) {
    const float* ap = agent + ((size_t)b * kAG + g) * kC + h * kD;
#pragma unroll
    for (int d4 = 0; d4 < 8; ++d4) {
      float4 v = *(const float4*)(ap + d4 * 4);
      ah[d4 * 4 + 0] = v.x; ah[d4 * 4 + 1] = v.y;
      ah[d4 * 4 + 2] = v.z; ah[d4 * 4 + 3] = v.w;
    }
  }
  float accv[kD] = {};
  float lsum = 0.f;

  for (int tile = 0; tile < kTPS; ++tile) {
    const int n0base = segBase + tile * kT;
    __syncthreads();  // protect prior tile's LDS readers
    for (int i = t; i < kT * 4; i += 256) {
      int row = i >> 2, j = i & 3;
      const unsigned short* rp =
          kv + ((size_t)b * kN + n0base + row) * kKV + h * kD + j * 8;
      ushort8 kf = *(const ushort8*)rp;
      ushort8 vf = *(const ushort8*)(rp + kC);
      int nq = row >> 2, e = row & 3;
#pragma unroll
      for (int q8 = 0; q8 < 8; ++q8) {
        KtT[j * 8 + q8][row] = bf2f(kf[q8]);
        Vt4[nq][j * 8 + q8][e] = bf2f(vf[q8]);
      }
    }
    __syncthreads();
    if (active) {
      const float* abp = abias + ((size_t)(h * kAG + g)) * kN + n0base + sub * 28;
#pragma unroll
      for (int k4 = 0; k4 < 7; ++k4) {
        float4 ab = *(const float4*)(abp + k4 * 4);
        float4 dot = {0.f, 0.f, 0.f, 0.f};
#pragma unroll
        for (int dd = 0; dd < kD; ++dd) {
          float a = ah[dd];
          float4 kt = *(const float4*)&KtT[dd][sub * 28 + k4 * 4];
          dot.x = fmaf(a, kt.x, dot.x);
          dot.y = fmaf(a, kt.y, dot.y);
          dot.z = fmaf(a, kt.z, dot.z);
          dot.w = fmaf(a, kt.w, dot.w);
        }
        float p0 = __expf(fmaf(dot.x, scale, ab.x));
        float p1 = __expf(fmaf(dot.y, scale, ab.y));
        float p2 = __expf(fmaf(dot.z, scale, ab.z));
        float p3 = __expf(fmaf(dot.w, scale, ab.w));
        lsum += (p0 + p1) + (p2 + p3);
        const int nq = 7 * sub + k4;
#pragma unroll
        for (int d = 0; d < kD; ++d) {
          const float4 vv = *(const float4*)&Vt4[nq][d][0];
          float s = accv[d];
          s = fmaf(p0, vv.x, s);
          s = fmaf(p1, vv.y, s);
          s = fmaf(p2, vv.z, s);
          s = fmaf(p3, vv.w, s);
          accv[d] = s;
        }
      }
    }
  }
  // cross-lane reduce within 4-lane agent group
#pragma unroll
  for (int d = 0; d < kD; ++d) {
    accv[d] += __shfl_xor(accv[d], 1);
    accv[d] += __shfl_xor(accv[d], 2);
  }
  lsum += __shfl_xor(lsum, 1);
  lsum += __shfl_xor(lsum, 2);
  if (active && sub == 0) {
    float* pb = part + (((size_t)(b * kH + h)) * kSEG + seg) * (kAG * kPART)
              + g * kPART;
    pb[0] = lsum;
#pragma unroll
    for (int d = 0; d < kD; ++d) pb[1 + d] = accv[d];
  }
}

// ------- merge the kSEG flash partials -> agent_v[b,h,a,d] (plain sums) -------
__global__ __launch_bounds__(256) void agent_merge_kernel(
    const float* __restrict__ part, float* __restrict__ agent_v) {
  int g = blockIdx.x * 256 + threadIdx.x;  // over nb*kH*kAG*kD
  int d = g & 31;
  int a = (g >> 5) % kAG;
  int bh = g / (kAG * kD);
  const float* pb = part + (((size_t)bh) * kSEG) * (kAG * kPART) + a * kPART;
  float den = 0.f, num = 0.f;
#pragma unroll
  for (int s = 0; s < kSEG; ++s) {
    const float* p = pb + s * kAG * kPART;
    den += p[0];
    num += p[1 + d];
  }
  agent_v[g] = num / den;
}

// ------- qbias(bf16)[h][a][n] = bilin(na) + ha[y,a] + wa[x,a] -------
__global__ __launch_bounds__(256) void qbias_kernel(
    const float* __restrict__ na_bias, const float* __restrict__ ha_bias,
    const float* __restrict__ wa_bias, unsigned short* __restrict__ qbias) {
  int ha = blockIdx.x;  // h*kAG + a
  int h = ha / kAG, a = ha % kAG;
  const float* tab = na_bias + ha * 49;
  for (int n = threadIdx.x; n < kN; n += 256) {
    int y = n / kHW, x = n % kHW;
    qbias[(size_t)ha * kN + n] = f2bf(bilin7(tab, y, x)
        + ha_bias[(h * kHW + y) * kAG + a]
        + wa_bias[(h * kHW + x) * kAG + a]);
  }
}

// --- q-attention v8: MFMA scores + MFMA PV, dwc tail; block=(b,h,256 rows) ---
// Wave computes 64x49 scores via 16 mfma_16x16x32_bf16 (agents padded to 64,
// pad cols forced P=0), exp+qbias in C layout, rowsum via 16-lane shfl, P
// relayout through per-wave LDS tile, PV via 16 MFMAs, normalized out to LDS,
// then thread-per-n dwc (v5 path). Fragment layouts identical to the GEMM.
__global__ __launch_bounds__(256) void qattn_v8_kernel(
    unsigned short* __restrict__ q, const unsigned short* __restrict__ kv,
    const float* __restrict__ agent, const float* __restrict__ agent_v,
    const unsigned short* __restrict__ qbias, const float* __restrict__ dwc_w,
    const float* __restrict__ dwc_b) {
  const int t = threadIdx.x;
  int lin = blockIdx.x + gridDim.x * (blockIdx.y + gridDim.y * blockIdx.z);
  const int h = lin & 7;                     // same-h blocks -> one XCD
  int rest = lin >> 3;
  const int n0 = (rest % kNT) * 256;
  const int b  = rest / kNT;
  const int w = t >> 6, lane = t & 63;
  const int lr = lane & 15, lg = lane >> 4;
  const float scale = 0.17677669529663687f;

  __shared__ unsigned short agsT[64 * 40];      // [a][d], pad a->64
  __shared__ unsigned short avsT[32 * 72];      // [d][a], pad a->64
  __shared__ unsigned short Pl[4 * 64 * 72];    // per-wave P (then out) [row][a]

  // zero-fill tables (covers agent pads)
  for (int i = t; i < 320; i += 256) *(ushort8*)&agsT[i * 8] = (ushort8)0;
  for (int i = t; i < 288; i += 256) *(ushort8*)&avsT[i * 8] = (ushort8)0;
  __syncthreads();
  // fill agsT[a][d] from agent (f32 -> bf16)
  for (int i = t; i < kAG * 4; i += 256) {
    int a = i >> 2, j = i & 3;
    const float* sp = agent + ((size_t)b * kAG + a) * kC + h * kD + j * 8;
    float4 f0 = *(const float4*)sp, f1 = *(const float4*)(sp + 4);
    ushort8 v;
    v[0] = f2bf(f0.x); v[1] = f2bf(f0.y); v[2] = f2bf(f0.z); v[3] = f2bf(f0.w);
    v[4] = f2bf(f1.x); v[5] = f2bf(f1.y); v[6] = f2bf(f1.z); v[7] = f2bf(f1.w);
    *(ushort8*)&agsT[a * 40 + j * 8] = v;
  }
  // fill avsT[d][a] from agent_v (transpose)
  for (int i = t; i < kAG * 8; i += 256) {
    int a = i >> 3, dj = i & 7;
    float4 f = *(const float4*)(agent_v + (((size_t)b * kH + h) * kAG + a) * kD + dj * 4);
    avsT[(dj * 4 + 0) * 72 + a] = f2bf(f.x);
    avsT[(dj * 4 + 1) * 72 + a] = f2bf(f.y);
    avsT[(dj * 4 + 2) * 72 + a] = f2bf(f.z);
    avsT[(dj * 4 + 3) * 72 + a] = f2bf(f.w);
  }
  __syncthreads();

  // ---- MFMA1: scores = q(64x32) @ agentT(32x64) ----
  short8 af[4];
#pragma unroll
  for (int rt = 0; rt < 4; ++rt) {
    int nr = n0 + w * 64 + rt * 16 + lr;
    nr = min(nr, kN - 1);
    af[rt] = *(const short8*)&q[((size_t)b * kN + nr) * kC + h * kD + lg * 8];
  }
  short8 bfr[4];
#pragma unroll
  for (int ct = 0; ct < 4; ++ct)
    bfr[ct] = *(const short8*)&agsT[(ct * 16 + lr) * 40 + lg * 8];
  f32x4 c[4][4] = {};
#pragma unroll
  for (int rt = 0; rt < 4; ++rt)
#pragma unroll
    for (int ct = 0; ct < 4; ++ct)
      c[rt][ct] = __builtin_amdgcn_mfma_f32_16x16x32_bf16(af[rt], bfr[ct],
                                                          c[rt][ct], 0, 0, 0);
  // ---- qbias + exp (pad cols -> 0) + row-sums ----
  f32x4 lsumv[4] = {};
#pragma unroll
  for (int rt = 0; rt < 4; ++rt) {
#pragma unroll
    for (int ct = 0; ct < 4; ++ct) {
      int col = ct * 16 + lr;
      bool valid = col < kAG;
      int nrow = n0 + w * 64 + rt * 16 + lg * 4;
      nrow = min(nrow, kN - 4);
      float qb[4] = {0.f, 0.f, 0.f, 0.f};
      if (valid) {
        uint2 qw = *(const uint2*)&qbias[((size_t)(h * kAG + col)) * kN + nrow];
        qb[0] = bf2f((unsigned short)(qw.x & 0xffff));
        qb[1] = bf2f((unsigned short)(qw.x >> 16));
        qb[2] = bf2f((unsigned short)(qw.y & 0xffff));
        qb[3] = bf2f((unsigned short)(qw.y >> 16));
      }
#pragma unroll
      for (int reg = 0; reg < 4; ++reg) {
        float pv = valid ? __expf(fmaf(c[rt][ct][reg], scale, qb[reg])) : 0.f;
        c[rt][ct][reg] = pv;
        lsumv[rt][reg] += pv;
      }
    }
  }
#pragma unroll
  for (int rt = 0; rt < 4; ++rt)
#pragma unroll
    for (int j = 0; j < 4; ++j) {
      float v = lsumv[rt][j];
      v += __shfl_xor(v, 1);
      v += __shfl_xor(v, 2);
      v += __shfl_xor(v, 4);
      v += __shfl_xor(v, 8);
      lsumv[rt][j] = v;
    }
  // ---- P -> per-wave LDS tile [row][a] bf16 ----
#pragma unroll
  for (int rt = 0; rt < 4; ++rt)
#pragma unroll
    for (int ct = 0; ct < 4; ++ct)
#pragma unroll
      for (int reg = 0; reg < 4; ++reg)
        Pl[(w * 64 + rt * 16 + lg * 4 + reg) * 72 + ct * 16 + lr] =
            f2bf(c[rt][ct][reg]);
  // ---- MFMA2: out = P(64x64) @ agent_v(64x32) ----
  short8 af2[4][2];
#pragma unroll
  for (int rt = 0; rt < 4; ++rt)
#pragma unroll
    for (int ks = 0; ks < 2; ++ks)
      af2[rt][ks] = *(const short8*)&Pl[(w * 64 + rt * 16 + lr) * 72 + ks * 32 + lg * 8];
  short8 bf2v[2][2];
#pragma unroll
  for (int ct2 = 0; ct2 < 2; ++ct2)
#pragma unroll
    for (int ks = 0; ks < 2; ++ks)
      bf2v[ct2][ks] = *(const short8*)&avsT[(ct2 * 16 + lr) * 72 + ks * 32 + lg * 8];
  f32x4 o[4][2] = {};
#pragma unroll
  for (int rt = 0; rt < 4; ++rt)
#pragma unroll
    for (int ct2 = 0; ct2 < 2; ++ct2)
#pragma unroll
      for (int ks = 0; ks < 2; ++ks)
        o[rt][ct2] = __builtin_amdgcn_mfma_f32_16x16x32_bf16(
            af2[rt][ks], bf2v[ct2][ks], o[rt][ct2], 0, 0, 0);
  // ---- normalize, write out (bf16) over the P tile ----
#pragma unroll
  for (int rt = 0; rt < 4; ++rt) {
    f32x4 inv;
#pragma unroll
    for (int j = 0; j < 4; ++j) inv[j] = 1.f / lsumv[rt][j];
#pragma unroll
    for (int ct2 = 0; ct2 < 2; ++ct2)
#pragma unroll
      for (int reg = 0; reg < 4; ++reg)
        Pl[(w * 64 + rt * 16 + lg * 4 + reg) * 72 + ct2 * 16 + lr] =
            f2bf(o[rt][ct2][reg] * inv[reg]);
  }
  // ---- dwc tail: thread t owns row n0+t (same-wave LDS region) ----
  const int n = n0 + t;
  if (n >= kN) return;
  float out[kD];
#pragma unroll
  for (int d8 = 0; d8 < 4; ++d8) {
    ushort8 v = *(const ushort8*)&Pl[t * 72 + d8 * 8];
#pragma unroll
    for (int e = 0; e < 8; ++e) out[d8 * 8 + e] = bf2f(v[e]);
  }
  const float* wb = dwc_w + (h * kD) * 9;
  const float* bb = dwc_b + h * kD;
#pragma unroll
  for (int d = 0; d < kD; ++d) out[d] += bb[d];
  const int y = n / kHW, x = n % kHW;
#pragma unroll
  for (int ky = 0; ky < 3; ++ky) {
    int yy = y + ky - 1;
    if (yy < 0 || yy >= kHW) continue;
#pragma unroll
    for (int kx = 0; kx < 3; ++kx) {
      int xx = x + kx - 1;
      if (xx < 0 || xx >= kHW) continue;
      const unsigned short* vp =
          kv + ((size_t)b * kN + yy * kHW + xx) * kKV + kC + h * kD;
#pragma unroll
      for (int d8 = 0; d8 < 4; ++d8) {
        ushort8 vv = *(const ushort8*)(vp + d8 * 8);
#pragma unroll
        for (int e = 0; e < 8; ++e)
          out[d8 * 8 + e] = fmaf(wb[(d8 * 8 + e) * 9 + ky * 3 + kx],
                                 bf2f(vv[e]), out[d8 * 8 + e]);
      }
    }
  }
  unsigned short* qp = q + ((size_t)b * kN + n) * kC + h * kD;
#pragma unroll
  for (int d8 = 0; d8 < 4; ++d8) {
    ushort8 v;
#pragma unroll
    for (int e = 0; e < 8; ++e) v[e] = f2bf(out[d8 * 8 + e]);
    *(ushort8*)(qp + d8 * 8) = v;
  }
}

extern "C" void kernel_launch(void* const* d_in, const int* in_sizes, int n_in,
                              void* d_out, int out_size, void* d_ws, size_t ws_size,
                              hipStream_t stream) {
  const float* x_f     = (const float*)d_in[0];
  const float* x_t     = (const float*)d_in[1];
  const float* Wq      = (const float*)d_in[2];
  const float* Wkv     = (const float*)d_in[3];
  const float* Wproj   = (const float*)d_in[4];
  const float* bproj   = (const float*)d_in[5];
  const float* dwc_w   = (const float*)d_in[6];
  const float* dwc_b   = (const float*)d_in[7];
  const float* an_bias = (const float*)d_in[8];
  const float* na_bias = (const float*)d_in[9];
  const float* ah_bias = (const float*)d_in[10];
  const float* aw_bias = (const float*)d_in[11];
  const float* ha_bias = (const float*)d_in[12];
  const float* wa_bias = (const float*)d_in[13];
  float* out           = (float*)d_out;  // reference output dtype is float32

  const size_t qbiasN = (size_t)kH * kAG * kN;  // elements per table
  const size_t perbB = (size_t)kN * kC * 2 + (size_t)kN * kKV * 2
                     + ((size_t)kAG * kC + (size_t)kH * kAG * kD
                        + (size_t)kH * kSEG * kAG * kPART) * 4;
  const size_t tabB = qbiasN * 2 + qbiasN * 4;  // qbias bf16 + abias f32
  if (ws_size < tabB) return;
  size_t fit = (ws_size - tabB) / perbB;
  int chunk = (int)(fit < 16 ? fit : 16);
  if (chunk < 1) return;

  char* p = (char*)d_ws;
  unsigned short* qbias = (unsigned short*)p;  p += qbiasN * 2;
  float* abias = (float*)p;                    p += qbiasN * 4;
  unsigned short* q  = (unsigned short*)p;     p += (size_t)chunk * kN * kC * 2;
  unsigned short* kv = (unsigned short*)p;     p += (size_t)chunk * kN * kKV * 2;
  float* agent  = (float*)p;                   p += (size_t)chunk * kAG * kC * 4;
  float* agentv = (float*)p;                   p += (size_t)chunk * kH * kAG * kD * 4;
  float* part   = (float*)p;

  qbias_kernel<<<kH * kAG, 256, 0, stream>>>(na_bias, ha_bias, wa_bias, qbias);
  abias_kernel<<<kH * kAG, 256, 0, stream>>>(an_bias, ah_bias, aw_bias, abias);

  for (int b0 = 0; b0 < kB; b0 += chunk) {
    int nb = (kB - b0) < chunk ? (kB - b0) : chunk;
    const int M = nb * kN;
    const float* xf_c = x_f + (size_t)b0 * kN * kC;
    const float* xt_c = x_t + (size_t)b0 * kN * kC;
    float* out_c = out + (size_t)b0 * kN * kC;

    gemm_mixed_kernel<false, true><<<dim3(kC / BN, M / BM), 256, 0, stream>>>(
        xf_c, Wq, nullptr, q, M, kC, kC);
    gemm_mixed_kernel<false, true><<<dim3(kKV / BN, M / BM), 256, 0, stream>>>(
        xt_c, Wkv, nullptr, kv, M, kKV, kC);
    pool_kernel<<<nb * kAG, 256, 0, stream>>>(q, agent);
    agent_attn_flash2_kernel<<<nb * kH * kSEG, 256, 0, stream>>>(agent, kv, abias, part);
    agent_merge_kernel<<<nb * kAG, 256, 0, stream>>>(part, agentv);
    qattn_v8_kernel<<<dim3(kNT, kH, nb), 256, 0, stream>>>(
        q, kv, agent, agentv, qbias, dwc_w, dwc_b);
    gemm_mixed_kernel<true, false><<<dim3(kC / BN, M / BM), 256, 0, stream>>>(
        q, Wproj, bproj, out_c, M, kC, kC);
  }
}

// Round 15
// 276.938 us; speedup vs baseline: 1.4623x; 1.2131x over previous
//
#include <hip/hip_runtime.h>
#include <hip/hip_bf16.h>

namespace {
constexpr int kB  = 16;
constexpr int kN  = 3136;
constexpr int kC  = 256;
constexpr int kH  = 8;     // heads
constexpr int kD  = 32;    // head dim
constexpr int kAG = 49;    // agents
constexpr int kHW = 56;
constexpr int kKV = 512;   // kv row stride (k cols 0..255, v cols 256..511)
constexpr int kT   = 112;  // flash tile (2 image rows)
constexpr int kSEG = 7;    // n-segments per (b,h)
constexpr int kTPS = kN / (kT * kSEG);  // 4 tiles per segment
constexpr int kPART = 33;  // per (b,h,seg,a): l, acc[32]

constexpr int BM = 128, BN = 128, BK = 64;
constexpr int LDK = BK + 8;   // bf16 row stride 72 (144 B)

constexpr int kNT = kN / 256 + 1;  // 13 n-tiles per (b,h)
}

typedef __attribute__((ext_vector_type(8))) short short8;
typedef __attribute__((ext_vector_type(8))) unsigned short ushort8;
typedef __attribute__((ext_vector_type(4))) float f32x4;

__device__ __forceinline__ unsigned short f2bf(float f) {
  union { float f; unsigned u; } v; v.f = f;
  unsigned r = (v.u + 0x7FFF + ((v.u >> 16) & 1)) >> 16;  // RNE
  return (unsigned short)r;
}
__device__ __forceinline__ float bf2f(unsigned short u) {
  union { unsigned u; float f; } v; v.u = ((unsigned)u) << 16;
  return v.f;
}

__device__ __forceinline__ float bilin7(const float* __restrict__ tab, int y, int x) {
  // jax.image.resize (7,7)->(56,56) bilinear, half-pixel centers, edge clamp.
  float fy = (y + 0.5f) * 0.125f - 0.5f;
  float fx = (x + 0.5f) * 0.125f - 0.5f;
  float fy0 = floorf(fy), fx0 = floorf(fx);
  float wy = fy - fy0, wx = fx - fx0;
  int y0 = (int)fy0, x0 = (int)fx0;
  int y0c = min(6, max(0, y0)),     x0c = min(6, max(0, x0));
  int y1c = min(6, max(0, y0 + 1)), x1c = min(6, max(0, x0 + 1));
  float v00 = tab[y0c * 7 + x0c], v01 = tab[y0c * 7 + x1c];
  float v10 = tab[y1c * 7 + x0c], v11 = tab[y1c * 7 + x1c];
  float top = v00 + wx * (v01 - v00);
  float bot = v10 + wx * (v11 - v10);
  return top + wy * (bot - top);
}

// ------- weight pre-transpose: Wt(bf16)[n][k] = bf16(W(f32)[k][n]) -------
__global__ __launch_bounds__(256) void wtrans_kernel(
    const float* __restrict__ W, unsigned short* __restrict__ Wt, int K, int N) {
  int idx = blockIdx.x * 256 + threadIdx.x;
  if (idx >= K * N) return;
  int n = idx / K, k = idx - n * K;  // write-coalesced along k
  Wt[idx] = f2bf(W[(size_t)k * N + n]);
}

// ---- bf16-MFMA GEMM: C = A @ Bt^T (+bias). A f32 or bf16; Bt bf16 [N][K]. ----
// Both A and B staging are coalesced loads + contiguous LDS stores (no
// transpose in-kernel; B was pre-transposed on device). XCD-swizzled grid.
template <bool ABF16, bool OUTBF16>
__global__ __launch_bounds__(256) void gemm_mixed_kernel(
    const void* __restrict__ Ap, const unsigned short* __restrict__ Bt,
    const float* __restrict__ bias, void* __restrict__ Cp,
    int M, int Nn, int K) {
  __shared__ unsigned short As[BM * LDK];
  __shared__ unsigned short Bs[BN * LDK];
  const int t = threadIdx.x;

  int tx = blockIdx.x, ty = blockIdx.y;
  {
    int nwg = gridDim.x * gridDim.y;
    if ((nwg & 7) == 0) {
      int bid = ty * gridDim.x + tx;
      int per8 = nwg >> 3;
      int lt = (bid & 7) * per8 + (bid >> 3);
      tx = lt % gridDim.x;
      ty = lt / gridDim.x;
    }
  }
  const int row0 = ty * BM;
  const int col0 = tx * BN;
  const int lane = t & 63;
  const int wid  = t >> 6;
  const int wrow = (wid >> 1) * 64;
  const int wcol = (wid & 1) * 64;
  const int lr = lane & 15, lg = lane >> 4;

  f32x4 acc[4][4] = {};

  for (int k0 = 0; k0 < K; k0 += BK) {
    __syncthreads();
    if constexpr (ABF16) {
      const unsigned short* A = (const unsigned short*)Ap;
#pragma unroll
      for (int i = 0; i < 4; ++i) {
        int idx = t + i * 256;
        int r = idx >> 3, k8 = (idx & 7) * 8;
        *(ushort8*)&As[r * LDK + k8] =
            *(const ushort8*)&A[(size_t)(row0 + r) * K + k0 + k8];
      }
    } else {
      const float* A = (const float*)Ap;
#pragma unroll
      for (int i = 0; i < 8; ++i) {
        int idx = t + i * 256;
        int r = idx >> 4, k4 = (idx & 15) * 4;
        float4 f = *(const float4*)&A[(size_t)(row0 + r) * K + k0 + k4];
        unsigned lo = (unsigned)f2bf(f.x) | ((unsigned)f2bf(f.y) << 16);
        unsigned hi = (unsigned)f2bf(f.z) | ((unsigned)f2bf(f.w) << 16);
        *(uint2*)&As[r * LDK + k4] = make_uint2(lo, hi);
      }
    }
    // stage B from pre-transposed bf16 Bt[n][k]: coalesced rows, contiguous
    // 16B LDS stores (identical pattern to the bf16 A path).
#pragma unroll
    for (int i = 0; i < 4; ++i) {
      int idx = t + i * 256;
      int r = idx >> 3, k8 = (idx & 7) * 8;
      *(ushort8*)&Bs[r * LDK + k8] =
          *(const ushort8*)&Bt[(size_t)(col0 + r) * K + k0 + k8];
    }
    __syncthreads();
#pragma unroll
    for (int ks = 0; ks < 2; ++ks) {
      short8 af[4], bf[4];
#pragma unroll
      for (int m = 0; m < 4; ++m)
        af[m] = *(const short8*)&As[(wrow + m * 16 + lr) * LDK + ks * 32 + lg * 8];
#pragma unroll
      for (int n = 0; n < 4; ++n)
        bf[n] = *(const short8*)&Bs[(wcol + n * 16 + lr) * LDK + ks * 32 + lg * 8];
#pragma unroll
      for (int m = 0; m < 4; ++m)
#pragma unroll
        for (int n = 0; n < 4; ++n)
          acc[m][n] = __builtin_amdgcn_mfma_f32_16x16x32_bf16(
              af[m], bf[n], acc[m][n], 0, 0, 0);
    }
  }
#pragma unroll
  for (int m = 0; m < 4; ++m) {
#pragma unroll
    for (int n = 0; n < 4; ++n) {
      int col = col0 + wcol + n * 16 + lr;
      float badd = bias ? bias[col] : 0.f;
#pragma unroll
      for (int j = 0; j < 4; ++j) {
        int row = row0 + wrow + m * 16 + lg * 4 + j;
        if constexpr (OUTBF16)
          ((unsigned short*)Cp)[(size_t)row * Nn + col] = f2bf(acc[m][n][j] + badd);
        else
          ((float*)Cp)[(size_t)row * Nn + col] = acc[m][n][j] + badd;
      }
    }
  }
}

// ------- 8x8 mean pool: q(bf16)[b,n,c] -> agent(f32)[b,a,c] (b relative) -------
__global__ __launch_bounds__(256) void pool_kernel(const unsigned short* __restrict__ q,
                                                   float* __restrict__ agent) {
  int blk = blockIdx.x;
  int b = blk / kAG, a = blk % kAG;
  int ho = a / 7, wo = a % 7;
  int c = threadIdx.x;
  float s = 0.f;
#pragma unroll
  for (int i = 0; i < 8; ++i) {
    int y = ho * 8 + i;
#pragma unroll
    for (int j = 0; j < 8; ++j) {
      int x = wo * 8 + j;
      s += bf2f(q[((size_t)b * kN + y * kHW + x) * kC + c]);
    }
  }
  agent[((size_t)b * kAG + a) * kC + c] = s * (1.f / 64.f);
}

// ------- abias[h][a][n] = bilin(an)[h,a,n] + ah[h,a,y] + aw[h,a,x] (f32) -------
__global__ __launch_bounds__(256) void abias_kernel(
    const float* __restrict__ an_bias, const float* __restrict__ ah_bias,
    const float* __restrict__ aw_bias, float* __restrict__ abias) {
  int ha = blockIdx.x;  // h*kAG + a
  const float* tab = an_bias + ha * 49;
  const float* ahb = ah_bias + ha * kHW;
  const float* awb = aw_bias + ha * kHW;
  for (int n = threadIdx.x; n < kN; n += 256) {
    int y = n / kHW, x = n % kHW;
    abias[(size_t)ha * kN + n] = bilin7(tab, y, x) + ahb[y] + awb[x];
  }
}

// ------- flash agent attention v2 (bf16 kv), segment pass -------
__global__ __launch_bounds__(256) void agent_attn_flash2_kernel(
    const float* __restrict__ agent, const unsigned short* __restrict__ kv,
    const float* __restrict__ abias, float* __restrict__ part) {
  const int blk = blockIdx.x;
  const int seg = blk % kSEG;
  const int h   = (blk / kSEG) % kH;
  const int b   = blk / (kSEG * kH);
  const int t   = threadIdx.x;
  const int sub = t & 3;        // lane within agent-group: owns n = sub*28+k
  const int g   = t >> 2;       // agent id (g<49 active)
  const bool active = g < kAG;

  __shared__ float KtT[kD][116];            // K transposed, stride 116
  __shared__ float Vt4[kT / 4][kD + 1][4];  // V n-packed: (n,d) -> [n>>2][d][n&3]

  const float scale = 0.17677669529663687f;
  const int segBase = seg * (kT * kTPS);

  float ah[kD];
  if (active) {
    const float* ap = agent + ((size_t)b * kAG + g) * kC + h * kD;
#pragma unroll
    for (int d4 = 0; d4 < 8; ++d4) {
      float4 v = *(const float4*)(ap + d4 * 4);
      ah[d4 * 4 + 0] = v.x; ah[d4 * 4 + 1] = v.y;
      ah[d4 * 4 + 2] = v.z; ah[d4 * 4 + 3] = v.w;
    }
  }
  float accv[kD] = {};
  float lsum = 0.f;

  for (int tile = 0; tile < kTPS; ++tile) {
    const int n0base = segBase + tile * kT;
    __syncthreads();  // protect prior tile's LDS readers
    for (int i = t; i < kT * 4; i += 256) {
      int row = i >> 2, j = i & 3;
      const unsigned short* rp =
          kv + ((size_t)b * kN + n0base + row) * kKV + h * kD + j * 8;
      ushort8 kf = *(const ushort8*)rp;
      ushort8 vf = *(const ushort8*)(rp + kC);
      int nq = row >> 2, e = row & 3;
#pragma unroll
      for (int q8 = 0; q8 < 8; ++q8) {
        KtT[j * 8 + q8][row] = bf2f(kf[q8]);
        Vt4[nq][j * 8 + q8][e] = bf2f(vf[q8]);
      }
    }
    __syncthreads();
    if (active) {
      const float* abp = abias + ((size_t)(h * kAG + g)) * kN + n0base + sub * 28;
#pragma unroll
      for (int k4 = 0; k4 < 7; ++k4) {
        float4 ab = *(const float4*)(abp + k4 * 4);
        float4 dot = {0.f, 0.f, 0.f, 0.f};
#pragma unroll
        for (int dd = 0; dd < kD; ++dd) {
          float a = ah[dd];
          float4 kt = *(const float4*)&KtT[dd][sub * 28 + k4 * 4];
          dot.x = fmaf(a, kt.x, dot.x);
          dot.y = fmaf(a, kt.y, dot.y);
          dot.z = fmaf(a, kt.z, dot.z);
          dot.w = fmaf(a, kt.w, dot.w);
        }
        float p0 = __expf(fmaf(dot.x, scale, ab.x));
        float p1 = __expf(fmaf(dot.y, scale, ab.y));
        float p2 = __expf(fmaf(dot.z, scale, ab.z));
        float p3 = __expf(fmaf(dot.w, scale, ab.w));
        lsum += (p0 + p1) + (p2 + p3);
        const int nq = 7 * sub + k4;
#pragma unroll
        for (int d = 0; d < kD; ++d) {
          const float4 vv = *(const float4*)&Vt4[nq][d][0];
          float s = accv[d];
          s = fmaf(p0, vv.x, s);
          s = fmaf(p1, vv.y, s);
          s = fmaf(p2, vv.z, s);
          s = fmaf(p3, vv.w, s);
          accv[d] = s;
        }
      }
    }
  }
  // cross-lane reduce within 4-lane agent group
#pragma unroll
  for (int d = 0; d < kD; ++d) {
    accv[d] += __shfl_xor(accv[d], 1);
    accv[d] += __shfl_xor(accv[d], 2);
  }
  lsum += __shfl_xor(lsum, 1);
  lsum += __shfl_xor(lsum, 2);
  if (active && sub == 0) {
    float* pb = part + (((size_t)(b * kH + h)) * kSEG + seg) * (kAG * kPART)
              + g * kPART;
    pb[0] = lsum;
#pragma unroll
    for (int d = 0; d < kD; ++d) pb[1 + d] = accv[d];
  }
}

// ------- merge the kSEG flash partials -> agent_v[b,h,a,d] (plain sums) -------
__global__ __launch_bounds__(256) void agent_merge_kernel(
    const float* __restrict__ part, float* __restrict__ agent_v) {
  int g = blockIdx.x * 256 + threadIdx.x;  // over nb*kH*kAG*kD
  int d = g & 31;
  int a = (g >> 5) % kAG;
  int bh = g / (kAG * kD);
  const float* pb = part + (((size_t)bh) * kSEG) * (kAG * kPART) + a * kPART;
  float den = 0.f, num = 0.f;
#pragma unroll
  for (int s = 0; s < kSEG; ++s) {
    const float* p = pb + s * kAG * kPART;
    den += p[0];
    num += p[1 + d];
  }
  agent_v[g] = num / den;
}

// ------- qbias(bf16)[h][a][n] = bilin(na) + ha[y,a] + wa[x,a] -------
__global__ __launch_bounds__(256) void qbias_kernel(
    const float* __restrict__ na_bias, const float* __restrict__ ha_bias,
    const float* __restrict__ wa_bias, unsigned short* __restrict__ qbias) {
  int ha = blockIdx.x;  // h*kAG + a
  int h = ha / kAG, a = ha % kAG;
  const float* tab = na_bias + ha * 49;
  for (int n = threadIdx.x; n < kN; n += 256) {
    int y = n / kHW, x = n % kHW;
    qbias[(size_t)ha * kN + n] = f2bf(bilin7(tab, y, x)
        + ha_bias[(h * kHW + y) * kAG + a]
        + wa_bias[(h * kHW + x) * kAG + a]);
  }
}

// --- q-attention v8: MFMA scores + MFMA PV, dwc tail; block=(b,h,256 rows) ---
__global__ __launch_bounds__(256) void qattn_v8_kernel(
    unsigned short* __restrict__ q, const unsigned short* __restrict__ kv,
    const float* __restrict__ agent, const float* __restrict__ agent_v,
    const unsigned short* __restrict__ qbias, const float* __restrict__ dwc_w,
    const float* __restrict__ dwc_b) {
  const int t = threadIdx.x;
  int lin = blockIdx.x + gridDim.x * (blockIdx.y + gridDim.y * blockIdx.z);
  const int h = lin & 7;                     // same-h blocks -> one XCD
  int rest = lin >> 3;
  const int n0 = (rest % kNT) * 256;
  const int b  = rest / kNT;
  const int w = t >> 6, lane = t & 63;
  const int lr = lane & 15, lg = lane >> 4;
  const float scale = 0.17677669529663687f;

  __shared__ unsigned short agsT[64 * 40];      // [a][d], pad a->64
  __shared__ unsigned short avsT[32 * 72];      // [d][a], pad a->64
  __shared__ unsigned short Pl[4 * 64 * 72];    // per-wave P (then out) [row][a]

  for (int i = t; i < 320; i += 256) *(ushort8*)&agsT[i * 8] = (ushort8)0;
  for (int i = t; i < 288; i += 256) *(ushort8*)&avsT[i * 8] = (ushort8)0;
  __syncthreads();
  for (int i = t; i < kAG * 4; i += 256) {
    int a = i >> 2, j = i & 3;
    const float* sp = agent + ((size_t)b * kAG + a) * kC + h * kD + j * 8;
    float4 f0 = *(const float4*)sp, f1 = *(const float4*)(sp + 4);
    ushort8 v;
    v[0] = f2bf(f0.x); v[1] = f2bf(f0.y); v[2] = f2bf(f0.z); v[3] = f2bf(f0.w);
    v[4] = f2bf(f1.x); v[5] = f2bf(f1.y); v[6] = f2bf(f1.z); v[7] = f2bf(f1.w);
    *(ushort8*)&agsT[a * 40 + j * 8] = v;
  }
  for (int i = t; i < kAG * 8; i += 256) {
    int a = i >> 3, dj = i & 7;
    float4 f = *(const float4*)(agent_v + (((size_t)b * kH + h) * kAG + a) * kD + dj * 4);
    avsT[(dj * 4 + 0) * 72 + a] = f2bf(f.x);
    avsT[(dj * 4 + 1) * 72 + a] = f2bf(f.y);
    avsT[(dj * 4 + 2) * 72 + a] = f2bf(f.z);
    avsT[(dj * 4 + 3) * 72 + a] = f2bf(f.w);
  }
  __syncthreads();

  // ---- MFMA1: scores = q(64x32) @ agentT(32x64) ----
  short8 af[4];
#pragma unroll
  for (int rt = 0; rt < 4; ++rt) {
    int nr = n0 + w * 64 + rt * 16 + lr;
    nr = min(nr, kN - 1);
    af[rt] = *(const short8*)&q[((size_t)b * kN + nr) * kC + h * kD + lg * 8];
  }
  short8 bfr[4];
#pragma unroll
  for (int ct = 0; ct < 4; ++ct)
    bfr[ct] = *(const short8*)&agsT[(ct * 16 + lr) * 40 + lg * 8];
  f32x4 c[4][4] = {};
#pragma unroll
  for (int rt = 0; rt < 4; ++rt)
#pragma unroll
    for (int ct = 0; ct < 4; ++ct)
      c[rt][ct] = __builtin_amdgcn_mfma_f32_16x16x32_bf16(af[rt], bfr[ct],
                                                          c[rt][ct], 0, 0, 0);
  // ---- qbias + exp (pad cols -> 0) + row-sums ----
  f32x4 lsumv[4] = {};
#pragma unroll
  for (int rt = 0; rt < 4; ++rt) {
#pragma unroll
    for (int ct = 0; ct < 4; ++ct) {
      int col = ct * 16 + lr;
      bool valid = col < kAG;
      int nrow = n0 + w * 64 + rt * 16 + lg * 4;
      nrow = min(nrow, kN - 4);
      float qb[4] = {0.f, 0.f, 0.f, 0.f};
      if (valid) {
        uint2 qw = *(const uint2*)&qbias[((size_t)(h * kAG + col)) * kN + nrow];
        qb[0] = bf2f((unsigned short)(qw.x & 0xffff));
        qb[1] = bf2f((unsigned short)(qw.x >> 16));
        qb[2] = bf2f((unsigned short)(qw.y & 0xffff));
        qb[3] = bf2f((unsigned short)(qw.y >> 16));
      }
#pragma unroll
      for (int reg = 0; reg < 4; ++reg) {
        float pv = valid ? __expf(fmaf(c[rt][ct][reg], scale, qb[reg])) : 0.f;
        c[rt][ct][reg] = pv;
        lsumv[rt][reg] += pv;
      }
    }
  }
#pragma unroll
  for (int rt = 0; rt < 4; ++rt)
#pragma unroll
    for (int j = 0; j < 4; ++j) {
      float v = lsumv[rt][j];
      v += __shfl_xor(v, 1);
      v += __shfl_xor(v, 2);
      v += __shfl_xor(v, 4);
      v += __shfl_xor(v, 8);
      lsumv[rt][j] = v;
    }
  // ---- P -> per-wave LDS tile [row][a] bf16 ----
#pragma unroll
  for (int rt = 0; rt < 4; ++rt)
#pragma unroll
    for (int ct = 0; ct < 4; ++ct)
#pragma unroll
      for (int reg = 0; reg < 4; ++reg)
        Pl[(w * 64 + rt * 16 + lg * 4 + reg) * 72 + ct * 16 + lr] =
            f2bf(c[rt][ct][reg]);
  // ---- MFMA2: out = P(64x64) @ agent_v(64x32) ----
  short8 af2[4][2];
#pragma unroll
  for (int rt = 0; rt < 4; ++rt)
#pragma unroll
    for (int ks = 0; ks < 2; ++ks)
      af2[rt][ks] = *(const short8*)&Pl[(w * 64 + rt * 16 + lr) * 72 + ks * 32 + lg * 8];
  short8 bf2v[2][2];
#pragma unroll
  for (int ct2 = 0; ct2 < 2; ++ct2)
#pragma unroll
    for (int ks = 0; ks < 2; ++ks)
      bf2v[ct2][ks] = *(const short8*)&avsT[(ct2 * 16 + lr) * 72 + ks * 32 + lg * 8];
  f32x4 o[4][2] = {};
#pragma unroll
  for (int rt = 0; rt < 4; ++rt)
#pragma unroll
    for (int ct2 = 0; ct2 < 2; ++ct2)
#pragma unroll
      for (int ks = 0; ks < 2; ++ks)
        o[rt][ct2] = __builtin_amdgcn_mfma_f32_16x16x32_bf16(
            af2[rt][ks], bf2v[ct2][ks], o[rt][ct2], 0, 0, 0);
  // ---- normalize, write out (bf16) over the P tile ----
#pragma unroll
  for (int rt = 0; rt < 4; ++rt) {
    f32x4 inv;
#pragma unroll
    for (int j = 0; j < 4; ++j) inv[j] = 1.f / lsumv[rt][j];
#pragma unroll
    for (int ct2 = 0; ct2 < 2; ++ct2)
#pragma unroll
      for (int reg = 0; reg < 4; ++reg)
        Pl[(w * 64 + rt * 16 + lg * 4 + reg) * 72 + ct2 * 16 + lr] =
            f2bf(o[rt][ct2][reg] * inv[reg]);
  }
  // ---- dwc tail: thread t owns row n0+t ----
  const int n = n0 + t;
  if (n >= kN) return;
  float out[kD];
#pragma unroll
  for (int d8 = 0; d8 < 4; ++d8) {
    ushort8 v = *(const ushort8*)&Pl[t * 72 + d8 * 8];
#pragma unroll
    for (int e = 0; e < 8; ++e) out[d8 * 8 + e] = bf2f(v[e]);
  }
  const float* wb = dwc_w + (h * kD) * 9;
  const float* bb = dwc_b + h * kD;
#pragma unroll
  for (int d = 0; d < kD; ++d) out[d] += bb[d];
  const int y = n / kHW, x = n % kHW;
#pragma unroll
  for (int ky = 0; ky < 3; ++ky) {
    int yy = y + ky - 1;
    if (yy < 0 || yy >= kHW) continue;
#pragma unroll
    for (int kx = 0; kx < 3; ++kx) {
      int xx = x + kx - 1;
      if (xx < 0 || xx >= kHW) continue;
      const unsigned short* vp =
          kv + ((size_t)b * kN + yy * kHW + xx) * kKV + kC + h * kD;
#pragma unroll
      for (int d8 = 0; d8 < 4; ++d8) {
        ushort8 vv = *(const ushort8*)(vp + d8 * 8);
#pragma unroll
        for (int e = 0; e < 8; ++e)
          out[d8 * 8 + e] = fmaf(wb[(d8 * 8 + e) * 9 + ky * 3 + kx],
                                 bf2f(vv[e]), out[d8 * 8 + e]);
      }
    }
  }
  unsigned short* qp = q + ((size_t)b * kN + n) * kC + h * kD;
#pragma unroll
  for (int d8 = 0; d8 < 4; ++d8) {
    ushort8 v;
#pragma unroll
    for (int e = 0; e < 8; ++e) v[e] = f2bf(out[d8 * 8 + e]);
    *(ushort8*)(qp + d8 * 8) = v;
  }
}

extern "C" void kernel_launch(void* const* d_in, const int* in_sizes, int n_in,
                              void* d_out, int out_size, void* d_ws, size_t ws_size,
                              hipStream_t stream) {
  const float* x_f     = (const float*)d_in[0];
  const float* x_t     = (const float*)d_in[1];
  const float* Wq      = (const float*)d_in[2];
  const float* Wkv     = (const float*)d_in[3];
  const float* Wproj   = (const float*)d_in[4];
  const float* bproj   = (const float*)d_in[5];
  const float* dwc_w   = (const float*)d_in[6];
  const float* dwc_b   = (const float*)d_in[7];
  const float* an_bias = (const float*)d_in[8];
  const float* na_bias = (const float*)d_in[9];
  const float* ah_bias = (const float*)d_in[10];
  const float* aw_bias = (const float*)d_in[11];
  const float* ha_bias = (const float*)d_in[12];
  const float* wa_bias = (const float*)d_in[13];
  float* out           = (float*)d_out;  // reference output dtype is float32

  const size_t qbiasN = (size_t)kH * kAG * kN;  // elements per table
  const size_t perbB = (size_t)kN * kC * 2 + (size_t)kN * kKV * 2
                     + ((size_t)kAG * kC + (size_t)kH * kAG * kD
                        + (size_t)kH * kSEG * kAG * kPART) * 4;
  // fixed tables: qbias bf16 + abias f32 + 3 transposed bf16 weights
  const size_t wtE = (size_t)kC * kC + (size_t)kC * kKV + (size_t)kC * kC;
  const size_t tabB = qbiasN * 2 + qbiasN * 4 + wtE * 2;
  if (ws_size < tabB) return;
  size_t fit = (ws_size - tabB) / perbB;
  int chunk = (int)(fit < 16 ? fit : 16);
  if (chunk < 1) return;

  char* p = (char*)d_ws;
  unsigned short* qbias = (unsigned short*)p;  p += qbiasN * 2;
  float* abias = (float*)p;                    p += qbiasN * 4;
  unsigned short* WqT   = (unsigned short*)p;  p += (size_t)kC * kC * 2;
  unsigned short* WkvT  = (unsigned short*)p;  p += (size_t)kC * kKV * 2;
  unsigned short* WprojT= (unsigned short*)p;  p += (size_t)kC * kC * 2;
  unsigned short* q  = (unsigned short*)p;     p += (size_t)chunk * kN * kC * 2;
  unsigned short* kv = (unsigned short*)p;     p += (size_t)chunk * kN * kKV * 2;
  float* agent  = (float*)p;                   p += (size_t)chunk * kAG * kC * 4;
  float* agentv = (float*)p;                   p += (size_t)chunk * kH * kAG * kD * 4;
  float* part   = (float*)p;

  qbias_kernel<<<kH * kAG, 256, 0, stream>>>(na_bias, ha_bias, wa_bias, qbias);
  abias_kernel<<<kH * kAG, 256, 0, stream>>>(an_bias, ah_bias, aw_bias, abias);
  wtrans_kernel<<<(kC * kC + 255) / 256, 256, 0, stream>>>(Wq, WqT, kC, kC);
  wtrans_kernel<<<(kC * kKV + 255) / 256, 256, 0, stream>>>(Wkv, WkvT, kC, kKV);
  wtrans_kernel<<<(kC * kC + 255) / 256, 256, 0, stream>>>(Wproj, WprojT, kC, kC);

  for (int b0 = 0; b0 < kB; b0 += chunk) {
    int nb = (kB - b0) < chunk ? (kB - b0) : chunk;
    const int M = nb * kN;
    const float* xf_c = x_f + (size_t)b0 * kN * kC;
    const float* xt_c = x_t + (size_t)b0 * kN * kC;
    float* out_c = out + (size_t)b0 * kN * kC;

    gemm_mixed_kernel<false, true><<<dim3(kC / BN, M / BM), 256, 0, stream>>>(
        xf_c, WqT, nullptr, q, M, kC, kC);
    gemm_mixed_kernel<false, true><<<dim3(kKV / BN, M / BM), 256, 0, stream>>>(
        xt_c, WkvT, nullptr, kv, M, kKV, kC);
    pool_kernel<<<nb * kAG, 256, 0, stream>>>(q, agent);
    agent_attn_flash2_kernel<<<nb * kH * kSEG, 256, 0, stream>>>(agent, kv, abias, part);
    agent_merge_kernel<<<nb * kAG, 256, 0, stream>>>(part, agentv);
    qattn_v8_kernel<<<dim3(kNT, kH, nb), 256, 0, stream>>>(
        q, kv, agent, agentv, qbias, dwc_w, dwc_b);
    gemm_mixed_kernel<true, false><<<dim3(kC / BN, M / BM), 256, 0, stream>>>(
        q, WprojT, bproj, out_c, M, kC, kC);
  }
}

// Round 16
// 219.155 us; speedup vs baseline: 1.8478x; 1.2637x over previous
//
#include <hip/hip_runtime.h>
#include <hip/hip_bf16.h>

namespace {
constexpr int kB  = 16;
constexpr int kN  = 3136;
constexpr int kC  = 256;
constexpr int kH  = 8;     // heads
constexpr int kD  = 32;    // head dim
constexpr int kAG = 49;    // agents
constexpr int kHW = 56;
constexpr int kKV = 512;   // kv row stride (k cols 0..255, v cols 256..511)
constexpr int kSEG = 7;    // n-segments per (b,h); 448 rows each
constexpr int kPART = 33;  // per (b,h,seg,a): l, acc[32]

constexpr int BM = 128, BN = 128, BK = 64;
constexpr int LDK = BK + 8;   // bf16 row stride 72 (144 B)

constexpr int kNT = kN / 256 + 1;  // 13 n-tiles per (b,h)
}

typedef __attribute__((ext_vector_type(8))) short short8;
typedef __attribute__((ext_vector_type(8))) unsigned short ushort8;
typedef __attribute__((ext_vector_type(4))) float f32x4;

__device__ __forceinline__ unsigned short f2bf(float f) {
  union { float f; unsigned u; } v; v.f = f;
  unsigned r = (v.u + 0x7FFF + ((v.u >> 16) & 1)) >> 16;  // RNE
  return (unsigned short)r;
}
__device__ __forceinline__ float bf2f(unsigned short u) {
  union { unsigned u; float f; } v; v.u = ((unsigned)u) << 16;
  return v.f;
}

__device__ __forceinline__ float bilin7(const float* __restrict__ tab, int y, int x) {
  // jax.image.resize (7,7)->(56,56) bilinear, half-pixel centers, edge clamp.
  float fy = (y + 0.5f) * 0.125f - 0.5f;
  float fx = (x + 0.5f) * 0.125f - 0.5f;
  float fy0 = floorf(fy), fx0 = floorf(fx);
  float wy = fy - fy0, wx = fx - fx0;
  int y0 = (int)fy0, x0 = (int)fx0;
  int y0c = min(6, max(0, y0)),     x0c = min(6, max(0, x0));
  int y1c = min(6, max(0, y0 + 1)), x1c = min(6, max(0, x0 + 1));
  float v00 = tab[y0c * 7 + x0c], v01 = tab[y0c * 7 + x1c];
  float v10 = tab[y1c * 7 + x0c], v11 = tab[y1c * 7 + x1c];
  float top = v00 + wx * (v01 - v00);
  float bot = v10 + wx * (v11 - v10);
  return top + wy * (bot - top);
}

// ------- weight pre-transpose: Wt(bf16)[n][k] = bf16(W(f32)[k][n]) -------
__global__ __launch_bounds__(256) void wtrans_kernel(
    const float* __restrict__ W, unsigned short* __restrict__ Wt, int K, int N) {
  int idx = blockIdx.x * 256 + threadIdx.x;
  if (idx >= K * N) return;
  int n = idx / K, k = idx - n * K;  // write-coalesced along k
  Wt[idx] = f2bf(W[(size_t)k * N + n]);
}

// ---- bf16-MFMA GEMM: C = A @ Bt^T (+bias). A f32 or bf16; Bt bf16 [N][K]. ----
template <bool ABF16, bool OUTBF16>
__global__ __launch_bounds__(256) void gemm_mixed_kernel(
    const void* __restrict__ Ap, const unsigned short* __restrict__ Bt,
    const float* __restrict__ bias, void* __restrict__ Cp,
    int M, int Nn, int K) {
  __shared__ unsigned short As[BM * LDK];
  __shared__ unsigned short Bs[BN * LDK];
  const int t = threadIdx.x;

  int tx = blockIdx.x, ty = blockIdx.y;
  {
    int nwg = gridDim.x * gridDim.y;
    if ((nwg & 7) == 0) {
      int bid = ty * gridDim.x + tx;
      int per8 = nwg >> 3;
      int lt = (bid & 7) * per8 + (bid >> 3);
      tx = lt % gridDim.x;
      ty = lt / gridDim.x;
    }
  }
  const int row0 = ty * BM;
  const int col0 = tx * BN;
  const int lane = t & 63;
  const int wid  = t >> 6;
  const int wrow = (wid >> 1) * 64;
  const int wcol = (wid & 1) * 64;
  const int lr = lane & 15, lg = lane >> 4;

  f32x4 acc[4][4] = {};

  for (int k0 = 0; k0 < K; k0 += BK) {
    __syncthreads();
    if constexpr (ABF16) {
      const unsigned short* A = (const unsigned short*)Ap;
#pragma unroll
      for (int i = 0; i < 4; ++i) {
        int idx = t + i * 256;
        int r = idx >> 3, k8 = (idx & 7) * 8;
        *(ushort8*)&As[r * LDK + k8] =
            *(const ushort8*)&A[(size_t)(row0 + r) * K + k0 + k8];
      }
    } else {
      const float* A = (const float*)Ap;
#pragma unroll
      for (int i = 0; i < 8; ++i) {
        int idx = t + i * 256;
        int r = idx >> 4, k4 = (idx & 15) * 4;
        float4 f = *(const float4*)&A[(size_t)(row0 + r) * K + k0 + k4];
        unsigned lo = (unsigned)f2bf(f.x) | ((unsigned)f2bf(f.y) << 16);
        unsigned hi = (unsigned)f2bf(f.z) | ((unsigned)f2bf(f.w) << 16);
        *(uint2*)&As[r * LDK + k4] = make_uint2(lo, hi);
      }
    }
#pragma unroll
    for (int i = 0; i < 4; ++i) {
      int idx = t + i * 256;
      int r = idx >> 3, k8 = (idx & 7) * 8;
      *(ushort8*)&Bs[r * LDK + k8] =
          *(const ushort8*)&Bt[(size_t)(col0 + r) * K + k0 + k8];
    }
    __syncthreads();
#pragma unroll
    for (int ks = 0; ks < 2; ++ks) {
      short8 af[4], bf[4];
#pragma unroll
      for (int m = 0; m < 4; ++m)
        af[m] = *(const short8*)&As[(wrow + m * 16 + lr) * LDK + ks * 32 + lg * 8];
#pragma unroll
      for (int n = 0; n < 4; ++n)
        bf[n] = *(const short8*)&Bs[(wcol + n * 16 + lr) * LDK + ks * 32 + lg * 8];
#pragma unroll
      for (int m = 0; m < 4; ++m)
#pragma unroll
        for (int n = 0; n < 4; ++n)
          acc[m][n] = __builtin_amdgcn_mfma_f32_16x16x32_bf16(
              af[m], bf[n], acc[m][n], 0, 0, 0);
    }
  }
#pragma unroll
  for (int m = 0; m < 4; ++m) {
#pragma unroll
    for (int n = 0; n < 4; ++n) {
      int col = col0 + wcol + n * 16 + lr;
      float badd = bias ? bias[col] : 0.f;
#pragma unroll
      for (int j = 0; j < 4; ++j) {
        int row = row0 + wrow + m * 16 + lg * 4 + j;
        if constexpr (OUTBF16)
          ((unsigned short*)Cp)[(size_t)row * Nn + col] = f2bf(acc[m][n][j] + badd);
        else
          ((float*)Cp)[(size_t)row * Nn + col] = acc[m][n][j] + badd;
      }
    }
  }
}

// ------- 8x8 mean pool: q(bf16)[b,n,c] -> agent(f32)[b,a,c] (b relative) -------
__global__ __launch_bounds__(256) void pool_kernel(const unsigned short* __restrict__ q,
                                                   float* __restrict__ agent) {
  int blk = blockIdx.x;
  int b = blk / kAG, a = blk % kAG;
  int ho = a / 7, wo = a % 7;
  int c = threadIdx.x;
  float s = 0.f;
#pragma unroll
  for (int i = 0; i < 8; ++i) {
    int y = ho * 8 + i;
#pragma unroll
    for (int j = 0; j < 8; ++j) {
      int x = wo * 8 + j;
      s += bf2f(q[((size_t)b * kN + y * kHW + x) * kC + c]);
    }
  }
  agent[((size_t)b * kAG + a) * kC + c] = s * (1.f / 64.f);
}

// ------- abias[h][a][n] = bilin(an)[h,a,n] + ah[h,a,y] + aw[h,a,x] (f32) -------
__global__ __launch_bounds__(256) void abias_kernel(
    const float* __restrict__ an_bias, const float* __restrict__ ah_bias,
    const float* __restrict__ aw_bias, float* __restrict__ abias) {
  int ha = blockIdx.x;  // h*kAG + a
  const float* tab = an_bias + ha * 49;
  const float* ahb = ah_bias + ha * kHW;
  const float* awb = aw_bias + ha * kHW;
  for (int n = threadIdx.x; n < kN; n += 256) {
    int y = n / kHW, x = n % kHW;
    abias[(size_t)ha * kN + n] = bilin7(tab, y, x) + ahb[y] + awb[x];
  }
}

// ------- flash agent attention v3: MFMA scores + MFMA PV -------
// block = (b,h,seg); 4 waves; wave w owns chunks {w, w+4, ...} of the seg's
// 14x32 rows. Per chunk: scores S^T[32][64a] via 8 MFMAs (A=K rows from
// global, B=agsT), exp+abias with pad-col masking, P -> per-wave Pa[64][40],
// PV via 8 MFMAs accumulating in C-regs (B=per-wave Vt[32][40] transposed).
// Cross-wave reduce in LDS, write per-seg partials (merge kernel unchanged).
__global__ __launch_bounds__(256) void agent_attn_flash3_kernel(
    const float* __restrict__ agent, const unsigned short* __restrict__ kv,
    const float* __restrict__ abias, float* __restrict__ part) {
  const int t = threadIdx.x;
  const int lin = blockIdx.x;
  const int h = lin & 7;           // same-h blocks round-robin -> one XCD
  const int r = lin >> 3;
  const int seg = r % kSEG;
  const int b = r / kSEG;
  const int w = t >> 6, lane = t & 63;
  const int lr = lane & 15, lg = lane >> 4;
  const float scale = 0.17677669529663687f;

  __shared__ char sh[36864];
  unsigned short* agsT = (unsigned short*)sh;                        // [64][40]
  unsigned short* Pa   = (unsigned short*)(sh + 5120) + w * 64 * 40; // per-wave
  unsigned short* Vt   = (unsigned short*)(sh + 25600) + w * 32 * 40;// per-wave
  float* lred = (float*)(sh + 35840);                                // [4][64]

  // stage agsT[a][d] (zero-pad a->64)
  for (int i = t; i < 320; i += 256) *(ushort8*)&agsT[i * 8] = (ushort8)0;
  __syncthreads();
  for (int i = t; i < kAG * 4; i += 256) {
    int a = i >> 2, j = i & 3;
    const float* sp = agent + ((size_t)b * kAG + a) * kC + h * kD + j * 8;
    float4 f0 = *(const float4*)sp, f1 = *(const float4*)(sp + 4);
    ushort8 v;
    v[0] = f2bf(f0.x); v[1] = f2bf(f0.y); v[2] = f2bf(f0.z); v[3] = f2bf(f0.w);
    v[4] = f2bf(f1.x); v[5] = f2bf(f1.y); v[6] = f2bf(f1.z); v[7] = f2bf(f1.w);
    *(ushort8*)&agsT[a * 40 + j * 8] = v;
  }
  __syncthreads();

  float ls[4] = {};
  f32x4 o[4][2] = {};
  const int nchunks = (w < 2) ? 4 : 3;
  for (int ci = 0; ci < nchunks; ++ci) {
    const int chunk = w + 4 * ci;
    const int nb0 = seg * 448 + chunk * 32;
    // ---- stage Vt[d][n'] (per-wave 32x32 transpose) ----
    {
      int n = lane & 31, d0 = (lane >> 5) * 16;
      const unsigned short* vp =
          kv + ((size_t)b * kN + nb0 + n) * kKV + kC + h * kD + d0;
      ushort8 v0 = *(const ushort8*)vp;
      ushort8 v1 = *(const ushort8*)(vp + 8);
#pragma unroll
      for (int e = 0; e < 8; ++e) Vt[(d0 + e) * 40 + n] = v0[e];
#pragma unroll
      for (int e = 0; e < 8; ++e) Vt[(d0 + 8 + e) * 40 + n] = v1[e];
    }
    // ---- scores: S^T[32][64a] = K(32x32) @ agsT^T ----
    short8 af0 = *(const short8*)&kv[((size_t)b * kN + nb0 + lr) * kKV + h * kD + lg * 8];
    short8 af1 = *(const short8*)&kv[((size_t)b * kN + nb0 + 16 + lr) * kKV + h * kD + lg * 8];
    f32x4 c[2][4] = {};
#pragma unroll
    for (int ct = 0; ct < 4; ++ct) {
      short8 bfr = *(const short8*)&agsT[(ct * 16 + lr) * 40 + lg * 8];
      c[0][ct] = __builtin_amdgcn_mfma_f32_16x16x32_bf16(af0, bfr, c[0][ct], 0, 0, 0);
      c[1][ct] = __builtin_amdgcn_mfma_f32_16x16x32_bf16(af1, bfr, c[1][ct], 0, 0, 0);
    }
    // ---- exp + abias (pad cols -> 0), accumulate lsum, write Pa[a][n'] ----
#pragma unroll
    for (int rt = 0; rt < 2; ++rt) {
#pragma unroll
      for (int ct = 0; ct < 4; ++ct) {
        int a = ct * 16 + lr;
        bool valid = a < kAG;
        float4 ab = {0.f, 0.f, 0.f, 0.f};
        if (valid)
          ab = *(const float4*)&abias[((size_t)(h * kAG + a)) * kN + nb0 + rt * 16 + lg * 4];
        unsigned lo, hi;
        {
          float p0 = valid ? __expf(fmaf(c[rt][ct][0], scale, ab.x)) : 0.f;
          float p1 = valid ? __expf(fmaf(c[rt][ct][1], scale, ab.y)) : 0.f;
          float p2 = valid ? __expf(fmaf(c[rt][ct][2], scale, ab.z)) : 0.f;
          float p3 = valid ? __expf(fmaf(c[rt][ct][3], scale, ab.w)) : 0.f;
          ls[ct] += (p0 + p1) + (p2 + p3);
          lo = (unsigned)f2bf(p0) | ((unsigned)f2bf(p1) << 16);
          hi = (unsigned)f2bf(p2) | ((unsigned)f2bf(p3) << 16);
        }
        *(uint2*)&Pa[a * 40 + rt * 16 + lg * 4] = make_uint2(lo, hi);
      }
    }
    // ---- PV: o[64a][32d] += P(64x32) @ Vt^T ----
    short8 bfv0 = *(const short8*)&Vt[(lr) * 40 + lg * 8];
    short8 bfv1 = *(const short8*)&Vt[(16 + lr) * 40 + lg * 8];
#pragma unroll
    for (int rt = 0; rt < 4; ++rt) {
      short8 afp = *(const short8*)&Pa[(rt * 16 + lr) * 40 + lg * 8];
      o[rt][0] = __builtin_amdgcn_mfma_f32_16x16x32_bf16(afp, bfv0, o[rt][0], 0, 0, 0);
      o[rt][1] = __builtin_amdgcn_mfma_f32_16x16x32_bf16(afp, bfv1, o[rt][1], 0, 0, 0);
    }
  }
  // ---- reduce lsum across lg within wave ----
#pragma unroll
  for (int ct = 0; ct < 4; ++ct) {
    ls[ct] += __shfl_xor(ls[ct], 16);
    ls[ct] += __shfl_xor(ls[ct], 32);
  }
  __syncthreads();  // all waves done with agsT/Pa/Vt -> overlay reduce bufs
  float* ored = (float*)sh;  // [4][64][33]
  if (lane < 16) {
#pragma unroll
    for (int ct = 0; ct < 4; ++ct) lred[w * 64 + ct * 16 + lane] = ls[ct];
  }
#pragma unroll
  for (int rt = 0; rt < 4; ++rt)
#pragma unroll
    for (int ct2 = 0; ct2 < 2; ++ct2)
#pragma unroll
      for (int reg = 0; reg < 4; ++reg)
        ored[(w * 64 + rt * 16 + lg * 4 + reg) * 33 + ct2 * 16 + lr] =
            o[rt][ct2][reg];
  __syncthreads();
  float* pb = part + (((size_t)(b * kH + h)) * kSEG + seg) * (kAG * kPART);
  if (t < kAG)
    pb[t * kPART] = lred[t] + lred[64 + t] + lred[128 + t] + lred[192 + t];
  for (int i = t; i < kAG * kD; i += 256) {
    int a = i >> 5, d = i & 31;
    float s = ored[a * 33 + d] + ored[(64 + a) * 33 + d]
            + ored[(128 + a) * 33 + d] + ored[(192 + a) * 33 + d];
    pb[a * kPART + 1 + d] = s;
  }
}

// ------- merge the kSEG flash partials -> agent_v[b,h,a,d] (plain sums) -------
__global__ __launch_bounds__(256) void agent_merge_kernel(
    const float* __restrict__ part, float* __restrict__ agent_v) {
  int g = blockIdx.x * 256 + threadIdx.x;  // over nb*kH*kAG*kD
  int d = g & 31;
  int a = (g >> 5) % kAG;
  int bh = g / (kAG * kD);
  const float* pb = part + (((size_t)bh) * kSEG) * (kAG * kPART) + a * kPART;
  float den = 0.f, num = 0.f;
#pragma unroll
  for (int s = 0; s < kSEG; ++s) {
    const float* p = pb + s * kAG * kPART;
    den += p[0];
    num += p[1 + d];
  }
  agent_v[g] = num / den;
}

// ------- qbias(bf16)[h][a][n] = bilin(na) + ha[y,a] + wa[x,a] -------
__global__ __launch_bounds__(256) void qbias_kernel(
    const float* __restrict__ na_bias, const float* __restrict__ ha_bias,
    const float* __restrict__ wa_bias, unsigned short* __restrict__ qbias) {
  int ha = blockIdx.x;  // h*kAG + a
  int h = ha / kAG, a = ha % kAG;
  const float* tab = na_bias + ha * 49;
  for (int n = threadIdx.x; n < kN; n += 256) {
    int y = n / kHW, x = n % kHW;
    qbias[(size_t)ha * kN + n] = f2bf(bilin7(tab, y, x)
        + ha_bias[(h * kHW + y) * kAG + a]
        + wa_bias[(h * kHW + x) * kAG + a]);
  }
}

// --- q-attention v8: MFMA scores + MFMA PV, dwc tail; block=(b,h,256 rows) ---
__global__ __launch_bounds__(256) void qattn_v8_kernel(
    unsigned short* __restrict__ q, const unsigned short* __restrict__ kv,
    const float* __restrict__ agent, const float* __restrict__ agent_v,
    const unsigned short* __restrict__ qbias, const float* __restrict__ dwc_w,
    const float* __restrict__ dwc_b) {
  const int t = threadIdx.x;
  int lin = blockIdx.x + gridDim.x * (blockIdx.y + gridDim.y * blockIdx.z);
  const int h = lin & 7;                     // same-h blocks -> one XCD
  int rest = lin >> 3;
  const int n0 = (rest % kNT) * 256;
  const int b  = rest / kNT;
  const int w = t >> 6, lane = t & 63;
  const int lr = lane & 15, lg = lane >> 4;
  const float scale = 0.17677669529663687f;

  __shared__ unsigned short agsT[64 * 40];      // [a][d], pad a->64
  __shared__ unsigned short avsT[32 * 72];      // [d][a], pad a->64
  __shared__ unsigned short Pl[4 * 64 * 72];    // per-wave P (then out) [row][a]

  for (int i = t; i < 320; i += 256) *(ushort8*)&agsT[i * 8] = (ushort8)0;
  for (int i = t; i < 288; i += 256) *(ushort8*)&avsT[i * 8] = (ushort8)0;
  __syncthreads();
  for (int i = t; i < kAG * 4; i += 256) {
    int a = i >> 2, j = i & 3;
    const float* sp = agent + ((size_t)b * kAG + a) * kC + h * kD + j * 8;
    float4 f0 = *(const float4*)sp, f1 = *(const float4*)(sp + 4);
    ushort8 v;
    v[0] = f2bf(f0.x); v[1] = f2bf(f0.y); v[2] = f2bf(f0.z); v[3] = f2bf(f0.w);
    v[4] = f2bf(f1.x); v[5] = f2bf(f1.y); v[6] = f2bf(f1.z); v[7] = f2bf(f1.w);
    *(ushort8*)&agsT[a * 40 + j * 8] = v;
  }
  for (int i = t; i < kAG * 8; i += 256) {
    int a = i >> 3, dj = i & 7;
    float4 f = *(const float4*)(agent_v + (((size_t)b * kH + h) * kAG + a) * kD + dj * 4);
    avsT[(dj * 4 + 0) * 72 + a] = f2bf(f.x);
    avsT[(dj * 4 + 1) * 72 + a] = f2bf(f.y);
    avsT[(dj * 4 + 2) * 72 + a] = f2bf(f.z);
    avsT[(dj * 4 + 3) * 72 + a] = f2bf(f.w);
  }
  __syncthreads();

  short8 af[4];
#pragma unroll
  for (int rt = 0; rt < 4; ++rt) {
    int nr = n0 + w * 64 + rt * 16 + lr;
    nr = min(nr, kN - 1);
    af[rt] = *(const short8*)&q[((size_t)b * kN + nr) * kC + h * kD + lg * 8];
  }
  short8 bfr[4];
#pragma unroll
  for (int ct = 0; ct < 4; ++ct)
    bfr[ct] = *(const short8*)&agsT[(ct * 16 + lr) * 40 + lg * 8];
  f32x4 c[4][4] = {};
#pragma unroll
  for (int rt = 0; rt < 4; ++rt)
#pragma unroll
    for (int ct = 0; ct < 4; ++ct)
      c[rt][ct] = __builtin_amdgcn_mfma_f32_16x16x32_bf16(af[rt], bfr[ct],
                                                          c[rt][ct], 0, 0, 0);
  f32x4 lsumv[4] = {};
#pragma unroll
  for (int rt = 0; rt < 4; ++rt) {
#pragma unroll
    for (int ct = 0; ct < 4; ++ct) {
      int col = ct * 16 + lr;
      bool valid = col < kAG;
      int nrow = n0 + w * 64 + rt * 16 + lg * 4;
      nrow = min(nrow, kN - 4);
      float qb[4] = {0.f, 0.f, 0.f, 0.f};
      if (valid) {
        uint2 qw = *(const uint2*)&qbias[((size_t)(h * kAG + col)) * kN + nrow];
        qb[0] = bf2f((unsigned short)(qw.x & 0xffff));
        qb[1] = bf2f((unsigned short)(qw.x >> 16));
        qb[2] = bf2f((unsigned short)(qw.y & 0xffff));
        qb[3] = bf2f((unsigned short)(qw.y >> 16));
      }
#pragma unroll
      for (int reg = 0; reg < 4; ++reg) {
        float pv = valid ? __expf(fmaf(c[rt][ct][reg], scale, qb[reg])) : 0.f;
        c[rt][ct][reg] = pv;
        lsumv[rt][reg] += pv;
      }
    }
  }
#pragma unroll
  for (int rt = 0; rt < 4; ++rt)
#pragma unroll
    for (int j = 0; j < 4; ++j) {
      float v = lsumv[rt][j];
      v += __shfl_xor(v, 1);
      v += __shfl_xor(v, 2);
      v += __shfl_xor(v, 4);
      v += __shfl_xor(v, 8);
      lsumv[rt][j] = v;
    }
#pragma unroll
  for (int rt = 0; rt < 4; ++rt)
#pragma unroll
    for (int ct = 0; ct < 4; ++ct)
#pragma unroll
      for (int reg = 0; reg < 4; ++reg)
        Pl[(w * 64 + rt * 16 + lg * 4 + reg) * 72 + ct * 16 + lr] =
            f2bf(c[rt][ct][reg]);
  short8 af2[4][2];
#pragma unroll
  for (int rt = 0; rt < 4; ++rt)
#pragma unroll
    for (int ks = 0; ks < 2; ++ks)
      af2[rt][ks] = *(const short8*)&Pl[(w * 64 + rt * 16 + lr) * 72 + ks * 32 + lg * 8];
  short8 bf2v[2][2];
#pragma unroll
  for (int ct2 = 0; ct2 < 2; ++ct2)
#pragma unroll
    for (int ks = 0; ks < 2; ++ks)
      bf2v[ct2][ks] = *(const short8*)&avsT[(ct2 * 16 + lr) * 72 + ks * 32 + lg * 8];
  f32x4 o[4][2] = {};
#pragma unroll
  for (int rt = 0; rt < 4; ++rt)
#pragma unroll
    for (int ct2 = 0; ct2 < 2; ++ct2)
#pragma unroll
      for (int ks = 0; ks < 2; ++ks)
        o[rt][ct2] = __builtin_amdgcn_mfma_f32_16x16x32_bf16(
            af2[rt][ks], bf2v[ct2][ks], o[rt][ct2], 0, 0, 0);
#pragma unroll
  for (int rt = 0; rt < 4; ++rt) {
    f32x4 inv;
#pragma unroll
    for (int j = 0; j < 4; ++j) inv[j] = 1.f / lsumv[rt][j];
#pragma unroll
    for (int ct2 = 0; ct2 < 2; ++ct2)
#pragma unroll
      for (int reg = 0; reg < 4; ++reg)
        Pl[(w * 64 + rt * 16 + lg * 4 + reg) * 72 + ct2 * 16 + lr] =
            f2bf(o[rt][ct2][reg] * inv[reg]);
  }
  const int n = n0 + t;
  if (n >= kN) return;
  float out[kD];
#pragma unroll
  for (int d8 = 0; d8 < 4; ++d8) {
    ushort8 v = *(const ushort8*)&Pl[t * 72 + d8 * 8];
#pragma unroll
    for (int e = 0; e < 8; ++e) out[d8 * 8 + e] = bf2f(v[e]);
  }
  const float* wb = dwc_w + (h * kD) * 9;
  const float* bb = dwc_b + h * kD;
#pragma unroll
  for (int d = 0; d < kD; ++d) out[d] += bb[d];
  const int y = n / kHW, x = n % kHW;
#pragma unroll
  for (int ky = 0; ky < 3; ++ky) {
    int yy = y + ky - 1;
    if (yy < 0 || yy >= kHW) continue;
#pragma unroll
    for (int kx = 0; kx < 3; ++kx) {
      int xx = x + kx - 1;
      if (xx < 0 || xx >= kHW) continue;
      const unsigned short* vp =
          kv + ((size_t)b * kN + yy * kHW + xx) * kKV + kC + h * kD;
#pragma unroll
      for (int d8 = 0; d8 < 4; ++d8) {
        ushort8 vv = *(const ushort8*)(vp + d8 * 8);
#pragma unroll
        for (int e = 0; e < 8; ++e)
          out[d8 * 8 + e] = fmaf(wb[(d8 * 8 + e) * 9 + ky * 3 + kx],
                                 bf2f(vv[e]), out[d8 * 8 + e]);
      }
    }
  }
  unsigned short* qp = q + ((size_t)b * kN + n) * kC + h * kD;
#pragma unroll
  for (int d8 = 0; d8 < 4; ++d8) {
    ushort8 v;
#pragma unroll
    for (int e = 0; e < 8; ++e) v[e] = f2bf(out[d8 * 8 + e]);
    *(ushort8*)(qp + d8 * 8) = v;
  }
}

extern "C" void kernel_launch(void* const* d_in, const int* in_sizes, int n_in,
                              void* d_out, int out_size, void* d_ws, size_t ws_size,
                              hipStream_t stream) {
  const float* x_f     = (const float*)d_in[0];
  const float* x_t     = (const float*)d_in[1];
  const float* Wq      = (const float*)d_in[2];
  const float* Wkv     = (const float*)d_in[3];
  const float* Wproj   = (const float*)d_in[4];
  const float* bproj   = (const float*)d_in[5];
  const float* dwc_w   = (const float*)d_in[6];
  const float* dwc_b   = (const float*)d_in[7];
  const float* an_bias = (const float*)d_in[8];
  const float* na_bias = (const float*)d_in[9];
  const float* ah_bias = (const float*)d_in[10];
  const float* aw_bias = (const float*)d_in[11];
  const float* ha_bias = (const float*)d_in[12];
  const float* wa_bias = (const float*)d_in[13];
  float* out           = (float*)d_out;  // reference output dtype is float32

  const size_t qbiasN = (size_t)kH * kAG * kN;  // elements per table
  const size_t perbB = (size_t)kN * kC * 2 + (size_t)kN * kKV * 2
                     + ((size_t)kAG * kC + (size_t)kH * kAG * kD
                        + (size_t)kH * kSEG * kAG * kPART) * 4;
  const size_t wtE = (size_t)kC * kC + (size_t)kC * kKV + (size_t)kC * kC;
  const size_t tabB = qbiasN * 2 + qbiasN * 4 + wtE * 2;
  if (ws_size < tabB) return;
  size_t fit = (ws_size - tabB) / perbB;
  int chunk = (int)(fit < 16 ? fit : 16);
  if (chunk < 1) return;

  char* p = (char*)d_ws;
  unsigned short* qbias = (unsigned short*)p;  p += qbiasN * 2;
  float* abias = (float*)p;                    p += qbiasN * 4;
  unsigned short* WqT   = (unsigned short*)p;  p += (size_t)kC * kC * 2;
  unsigned short* WkvT  = (unsigned short*)p;  p += (size_t)kC * kKV * 2;
  unsigned short* WprojT= (unsigned short*)p;  p += (size_t)kC * kC * 2;
  unsigned short* q  = (unsigned short*)p;     p += (size_t)chunk * kN * kC * 2;
  unsigned short* kv = (unsigned short*)p;     p += (size_t)chunk * kN * kKV * 2;
  float* agent  = (float*)p;                   p += (size_t)chunk * kAG * kC * 4;
  float* agentv = (float*)p;                   p += (size_t)chunk * kH * kAG * kD * 4;
  float* part   = (float*)p;

  qbias_kernel<<<kH * kAG, 256, 0, stream>>>(na_bias, ha_bias, wa_bias, qbias);
  abias_kernel<<<kH * kAG, 256, 0, stream>>>(an_bias, ah_bias, aw_bias, abias);
  wtrans_kernel<<<(kC * kC + 255) / 256, 256, 0, stream>>>(Wq, WqT, kC, kC);
  wtrans_kernel<<<(kC * kKV + 255) / 256, 256, 0, stream>>>(Wkv, WkvT, kC, kKV);
  wtrans_kernel<<<(kC * kC + 255) / 256, 256, 0, stream>>>(Wproj, WprojT, kC, kC);

  for (int b0 = 0; b0 < kB; b0 += chunk) {
    int nb = (kB - b0) < chunk ? (kB - b0) : chunk;
    const int M = nb * kN;
    const float* xf_c = x_f + (size_t)b0 * kN * kC;
    const float* xt_c = x_t + (size_t)b0 * kN * kC;
    float* out_c = out + (size_t)b0 * kN * kC;

    gemm_mixed_kernel<false, true><<<dim3(kC / BN, M / BM), 256, 0, stream>>>(
        xf_c, WqT, nullptr, q, M, kC, kC);
    gemm_mixed_kernel<false, true><<<dim3(kKV / BN, M / BM), 256, 0, stream>>>(
        xt_c, WkvT, nullptr, kv, M, kKV, kC);
    pool_kernel<<<nb * kAG, 256, 0, stream>>>(q, agent);
    agent_attn_flash3_kernel<<<nb * kH * kSEG, 256, 0, stream>>>(agent, kv, abias, part);
    agent_merge_kernel<<<nb * kAG, 256, 0, stream>>>(part, agentv);
    qattn_v8_kernel<<<dim3(kNT, kH, nb), 256, 0, stream>>>(
        q, kv, agent, agentv, qbias, dwc_w, dwc_b);
    gemm_mixed_kernel<true, false><<<dim3(kC / BN, M / BM), 256, 0, stream>>>(
        q, WprojT, bproj, out_c, M, kC, kC);
  }
}